// Round 1
// baseline (1158.397 us; speedup 1.0000x reference)
//
#include <hip/hip_runtime.h>
#include <math.h>

// Problem dims (fixed by setup_inputs)
#define DD    512
#define CNUM  64
#define SHOTS 16
#define NSUP  1024
#define QNQ   2048
#define REGP  0.1f

// ---------------- workspace layout (in floats) ----------------
static constexpr size_t OFF_L     = 0;                       // 512*512
static constexpr size_t OFF_W     = OFF_L     + 512*512;     // 512*512
static constexpr size_t OFF_MU    = OFF_W     + 512*512;     // 64*512
static constexpr size_t OFF_Y     = OFF_MU    + 64*512;      // 3136*512 (Yq|Ys|Ymu)
static constexpr size_t OFF_Z     = OFF_Y     + 3136*512;    // 3136
static constexpr size_t OFF_WM    = OFF_Z     + 3136;        // 512
static constexpr size_t OFF_U     = OFF_WM    + 512;         // 512
static constexpr size_t OFF_CONST = OFF_U     + 512;         // 32
static constexpr size_t OFF_IDX   = OFF_CONST + 32;          // 1024 ints
static constexpr size_t OFF_YG    = OFF_IDX   + 1024;        // 1088*512
static constexpr size_t OFF_ZG    = OFF_YG    + 1088*512;    // 1088
static constexpr size_t OFF_VMU   = OFF_ZG    + 1088;        // 1088
static constexpr size_t OFF_MUBMU = OFF_VMU   + 1088;        // 64
static constexpr size_t OFF_MUN   = OFF_MUBMU + 64;          // 64
static constexpr size_t OFF_G     = OFF_MUN   + 64;          // 64*289
static constexpr size_t OFF_MINV  = OFF_G     + 64*289;      // 64*289
static constexpr size_t OFF_BIAS  = OFF_MINV  + 64*289;      // 64
static constexpr size_t OFF_QB    = OFF_BIAS  + 64;          // 2048
static constexpr size_t OFF_QNRM  = OFF_QB    + 2048;        // 2048
static constexpr size_t OFF_XMU   = OFF_QNRM  + 2048;        // 2048*64
static constexpr size_t OFF_RG    = OFF_XMU   + 2048*64;     // 1088*2048
static constexpr size_t WS_FLOATS = OFF_RG    + 1088*2048;   // ~5.13M floats (~20.5 MB)

// consts indices: 0 kap, 1 scale, 2 common, 3 coef, 4 bias0, 5 jlast,
// 6 cmu_m, 7 cmu_x, 8 D*log(scale), 9 Jinv_last, 10 c_sm, 11 logdetB

// ---------------- scalar setup ----------------
__global__ void k_consts(const float* kappa, const float* nu, float* cst) {
  float kap = fabsf(kappa[0]) + 1e-6f;
  float nu_ = fmaxf(nu[0], (float)(DD - 1) + 1e-6f);
  float common = nu_ + (float)SHOTS + 1.0f - (float)DD;
  float scale = (kap + SHOTS + 1.0f) / ((nu_ + SHOTS - DD + 1.0f) * (kap + SHOTS));
  cst[0] = kap;
  cst[1] = scale;
  cst[2] = common;
  cst[3] = 0.5f * (common + DD);
  cst[4] = lgammaf(0.5f * (common + DD)) - lgammaf(0.5f * common)
           - 0.5f * (float)DD * logf(common);
  cst[5] = -(kap + SHOTS);             // det(J) = jlast
  cst[6] = kap / (kap + SHOTS);        // mu: m coefficient
  cst[7] = 1.0f / (kap + SHOTS);       // mu: sum(X) coefficient
  cst[8] = (float)DD * logf(scale);
  cst[9] = -1.0f / (kap + SHOTS);      // J^{-1} last diagonal
}

__global__ void k_buildL(const float* tdiag, const float* tlow, float* L) {
  int t = blockIdx.x * 256 + threadIdx.x;
  if (t >= DD * DD) return;
  int i = t / DD, j = t % DD;
  L[t] = (i == j) ? fabsf(tdiag[i]) : (i > j ? tlow[t] : 0.0f);
}

__global__ void k_zero(float* p, size_t n) {
  size_t t = (size_t)blockIdx.x * 256 + threadIdx.x;
  if (t < n) p[t] = 0.0f;
}

// stable per-class index lists (argsort(labels) equivalent for balanced episode)
__global__ void k_classidx(const int* labels, int* idx) {
  int c = threadIdx.x;
  int cnt = 0;
  for (int i = 0; i < NSUP && cnt < SHOTS; i++)
    if (labels[i] == c) idx[c * SHOTS + cnt++] = i;
}

__global__ void k_mu(const float* Xs, const float* m, const int* idx,
                     const float* cst, float* mu) {
  int c = blockIdx.x;
  float cm = cst[6], cx = cst[7];
  for (int d = threadIdx.x; d < DD; d += 256) {
    float s = 0.0f;
    for (int sh = 0; sh < SHOTS; sh++)
      s += Xs[(size_t)idx[c * SHOTS + sh] * DD + d];
    mu[(size_t)c * DD + d] = cm * m[d] + cx * s;
  }
}

// ---------------- blocked triangular inverse W = L^{-1} ----------------
__global__ __launch_bounds__(64) void k_trinv_diag(const float* L, float* W) {
  __shared__ float Ld[64][65];
  __shared__ float Wd[64][65];
  int jb = blockIdx.x, t = threadIdx.x;
  const float* Lblk = L + (size_t)(jb * 64) * DD + jb * 64;
  for (int r = 0; r < 64; r++) Ld[r][t] = Lblk[(size_t)r * DD + t];
  __syncthreads();
  // thread t owns column t; only reads its own column's earlier rows
  for (int i = 0; i < 64; i++) {
    float w = (i == t) ? 1.0f : 0.0f;
    for (int k = 0; k < i; k++) w -= Ld[i][k] * Wd[k][t];
    Wd[i][t] = w / Ld[i][i];
  }
  __syncthreads();
  float* Wblk = W + (size_t)(jb * 64) * DD + jb * 64;
  for (int r = 0; r < 64; r++) Wblk[(size_t)r * DD + t] = Wd[r][t];
}

// level lev: W[i][j] = -W_ii * (sum_{k=j}^{i-1} L_ik W_kj), i = j + lev
__global__ __launch_bounds__(256) void k_trinv_off(const float* L, float* W, int lev) {
  __shared__ float Ls[64][65];
  __shared__ float Ws[64][65];
  int j = blockIdx.x, i = j + lev;
  int tid = threadIdx.x, tr = tid / 16, tc = tid % 16;
  float acc[4][4] = {};
  for (int kb = j; kb < i; kb++) {
    for (int p = 0; p < 16; p++) {
      int t = tid + 256 * p; int r = t / 64, cc = t % 64;
      Ls[r][cc] = L[(size_t)(i * 64 + r) * DD + kb * 64 + cc];
      Ws[r][cc] = W[(size_t)(kb * 64 + r) * DD + j * 64 + cc];
    }
    __syncthreads();
    for (int k = 0; k < 64; k++) {
      float a[4], b[4];
      for (int x = 0; x < 4; x++) a[x] = Ls[tr * 4 + x][k];
      for (int y = 0; y < 4; y++) b[y] = Ws[k][tc * 4 + y];
      for (int x = 0; x < 4; x++)
        for (int y = 0; y < 4; y++) acc[x][y] += a[x] * b[y];
    }
    __syncthreads();
  }
  // T -> Ls, W_ii -> Ws, then W_ij = -W_ii * T
  for (int x = 0; x < 4; x++)
    for (int y = 0; y < 4; y++) Ls[tr * 4 + x][tc * 4 + y] = acc[x][y];
  for (int p = 0; p < 16; p++) {
    int t = tid + 256 * p; int r = t / 64, cc = t % 64;
    Ws[r][cc] = W[(size_t)(i * 64 + r) * DD + i * 64 + cc];
  }
  __syncthreads();
  float out[4][4] = {};
  for (int k = 0; k < 64; k++) {
    float a[4], b[4];
    for (int x = 0; x < 4; x++) a[x] = Ws[tr * 4 + x][k];
    for (int y = 0; y < 4; y++) b[y] = Ls[k][tc * 4 + y];
    for (int x = 0; x < 4; x++)
      for (int y = 0; y < 4; y++) out[x][y] += a[x] * b[y];
  }
  for (int x = 0; x < 4; x++)
    for (int y = 0; y < 4; y++)
      W[(size_t)(i * 64 + tr * 4 + x) * DD + j * 64 + tc * 4 + y] = -out[x][y];
}

// ---------------- Sherman-Morrison pieces ----------------
__global__ void k_wm(const float* W, const float* m, float* wm) {
  int row = blockIdx.x, lane = threadIdx.x;
  float s = 0.0f;
  for (int j = lane; j < DD; j += 64) s += W[(size_t)row * DD + j] * m[j];
  for (int off = 32; off > 0; off >>= 1) s += __shfl_down(s, off);
  if (lane == 0) wm[row] = s;
}

__global__ void k_u(const float* W, const float* wm, float* u) {
  int j = blockIdx.x, lane = threadIdx.x;
  float s = 0.0f;
  for (int i = lane; i < DD; i += 64) s += W[(size_t)i * DD + j] * wm[i];
  for (int off = 32; off > 0; off >>= 1) s += __shfl_down(s, off);
  if (lane == 0) u[j] = s;
}

__global__ void k_smconsts(const float* L, const float* wm, float* cst) {
  __shared__ float s1[512], s2[512];
  int t = threadIdx.x;
  float a = wm[t] * wm[t];
  float b = logf(fabsf(L[(size_t)t * DD + t]));
  s1[t] = a; s2[t] = b;
  __syncthreads();
  for (int off = 256; off > 0; off >>= 1) {
    if (t < off) { s1[t] += s1[t + off]; s2[t] += s2[t + off]; }
    __syncthreads();
  }
  if (t == 0) {
    float kap = cst[0], ss = s1[0];
    cst[10] = kap / (1.0f + kap * ss);                // Sherman-Morrison coeff
    cst[11] = 2.0f * s2[0] + logf(1.0f + kap * ss);   // logdet(B)
  }
}

// ---------------- fp32 NT GEMM: C[M,N] = A[M,K] * B[N,K]^T ----------------
#define GBM 128
#define GBN 64
#define GBK 16
__global__ __launch_bounds__(256) void gemm_nt(const float* __restrict__ A,
                                               const float* __restrict__ B,
                                               float* __restrict__ Cc,
                                               int M, int N, int K) {
  __shared__ float As[GBK][GBM + 1];
  __shared__ float Bs[GBK][GBN + 1];
  int bm = blockIdx.y * GBM, bn = blockIdx.x * GBN;
  int tid = threadIdx.x, tr = tid / 16, tc = tid % 16;
  float acc[8][4] = {};
  for (int k0 = 0; k0 < K; k0 += GBK) {
    for (int p = 0; p < 8; p++) {
      int t = tid + 256 * p; int row = t / GBK, kk = t % GBK;
      int gr = bm + row;
      As[kk][row] = (gr < M) ? A[(size_t)gr * K + k0 + kk] : 0.0f;
    }
    for (int p = 0; p < 4; p++) {
      int t = tid + 256 * p; int row = t / GBK, kk = t % GBK;
      int gc = bn + row;
      Bs[kk][row] = (gc < N) ? B[(size_t)gc * K + k0 + kk] : 0.0f;
    }
    __syncthreads();
    for (int kk = 0; kk < GBK; kk++) {
      float a[8], b[4];
      for (int x = 0; x < 8; x++) a[x] = As[kk][tr * 8 + x];
      for (int y = 0; y < 4; y++) b[y] = Bs[kk][tc * 4 + y];
      for (int x = 0; x < 8; x++)
        for (int y = 0; y < 4; y++) acc[x][y] += a[x] * b[y];
    }
    __syncthreads();
  }
  for (int x = 0; x < 8; x++) {
    int gr = bm + tr * 8 + x;
    if (gr >= M) continue;
    for (int y = 0; y < 4; y++) {
      int gc = bn + tc * 4 + y;
      if (gc < N) Cc[(size_t)gr * N + gc] = acc[x][y];
    }
  }
}

// z[r] = F_r . u  over F = [Xq; Xs; mu]
__global__ void k_z(const float* Xq, const float* Xs, const float* mu,
                    const float* u, float* z) {
  int wave = threadIdx.x / 64, lane = threadIdx.x % 64;
  int row = blockIdx.x * 4 + wave;
  if (row >= 3136) return;
  const float* src = (row < QNQ) ? Xq + (size_t)row * DD
                   : (row < QNQ + NSUP) ? Xs + (size_t)(row - QNQ) * DD
                   : mu + (size_t)(row - QNQ - NSUP) * DD;
  float s = 0.0f;
  for (int j = lane; j < DD; j += 64) s += src[j] * u[j];
  for (int off = 32; off > 0; off >>= 1) s += __shfl_down(s, off);
  if (lane == 0) z[row] = s;
}

__global__ void k_gather(const float* Y, const float* z, const int* idx,
                         float* Yg, float* zg) {
  int b = blockIdx.x; int c = b / 17, a = b % 17;
  int src = (a < 16) ? (QNQ + idx[c * SHOTS + a]) : (QNQ + NSUP + c);
  const float* yr = Y + (size_t)src * DD;
  float* yo = Yg + (size_t)b * DD;
  for (int j = threadIdx.x; j < DD; j += 64) yo[j] = yr[j];
  if (threadIdx.x == 0) zg[b] = z[src];
}

// per-class 17x17 Gram (Binv inner products), M = Gram + J^{-1}
__global__ __launch_bounds__(256) void k_gram(const float* Yg, const float* zg,
                                              const float* cst, float* G,
                                              float* Vmu, float* muBmu) {
  __shared__ float Ys[17 * 513];
  __shared__ float zs[17];
  __shared__ float Gs[289];
  int c = blockIdx.x, tid = threadIdx.x;
  for (int t = tid; t < 17 * 512; t += 256) {
    int r = t >> 9, col = t & 511;
    Ys[r * 513 + col] = Yg[((size_t)c * 17 + r) * DD + col];
  }
  if (tid < 17) zs[tid] = zg[c * 17 + tid];
  __syncthreads();
  float csm = cst[10];
  for (int e = tid; e < 289; e += 256) {
    int a = e / 17, b = e % 17;
    const float* ra = &Ys[a * 513];
    const float* rb = &Ys[b * 513];
    float s = 0.0f;
    for (int k = 0; k < 512; k++) s += ra[k] * rb[k];
    Gs[e] = s - csm * zs[a] * zs[b];
  }
  __syncthreads();
  if (tid < 17) Vmu[c * 17 + tid] = Gs[tid * 17 + 16];
  if (tid == 0) muBmu[c] = Gs[16 * 17 + 16];
  __syncthreads();
  if (tid < 17) Gs[tid * 17 + tid] += (tid < 16) ? 1.0f : cst[9];
  __syncthreads();
  for (int t = tid; t < 289; t += 256) G[(size_t)c * 289 + t] = Gs[t];
}

// per-class Gauss-Jordan inverse of M (17x17) + logdet -> bias
__global__ __launch_bounds__(64) void k_minv(const float* G, const float* cst,
                                             float* Minv, float* bias) {
  __shared__ float aug[17][35];
  __shared__ float colk[17];
  __shared__ int pivrow;
  __shared__ float detacc[2];   // [0]=logdet, [1]=sign
  int c = blockIdx.x, lane = threadIdx.x;
  for (int t = lane; t < 289; t += 64) aug[t / 17][t % 17] = G[(size_t)c * 289 + t];
  for (int t = lane; t < 289; t += 64) aug[t / 17][17 + t % 17] = (t / 17 == t % 17) ? 1.0f : 0.0f;
  if (lane == 0) { detacc[0] = 0.0f; detacc[1] = 1.0f; }
  __syncthreads();
  for (int k = 0; k < 17; k++) {
    if (lane == 0) {
      int p = k; float best = fabsf(aug[k][k]);
      for (int r = k + 1; r < 17; r++) {
        float v = fabsf(aug[r][k]);
        if (v > best) { best = v; p = r; }
      }
      pivrow = p;
    }
    __syncthreads();
    int p = pivrow;
    if (p != k) {
      for (int cc = lane; cc < 34; cc += 64) {
        float tmp = aug[k][cc]; aug[k][cc] = aug[p][cc]; aug[p][cc] = tmp;
      }
    }
    __syncthreads();
    if (lane == 0) {
      float piv = aug[k][k];
      detacc[0] += logf(fabsf(piv));
      if (piv < 0.0f) detacc[1] = -detacc[1];
      if (p != k) detacc[1] = -detacc[1];
    }
    if (lane < 17) colk[lane] = aug[lane][k];
    __syncthreads();
    float invp = 1.0f / aug[k][k];
    for (int cc = lane; cc < 34; cc += 64) aug[k][cc] *= invp;
    __syncthreads();
    for (int t = lane; t < 17 * 34; t += 64) {
      int r = t / 34, cc = t % 34;
      if (r != k) aug[r][cc] -= colk[r] * aug[k][cc];
    }
    __syncthreads();
  }
  for (int t = lane; t < 289; t += 64) Minv[(size_t)c * 289 + t] = aug[t / 17][17 + t % 17];
  if (lane == 0) {
    // logdet(sigma_c) = D*log(scale) + logdet(B) + log(det(J)*det(M))
    float slog = logf(fabsf(cst[5])) + detacc[0];  // sign(J det * M det) > 0 (sigma PD)
    float logdetSigma = cst[8] + cst[11] + slog;
    bias[c] = cst[4] - 0.5f * logdetSigma;
  }
}

// per-query norms: qn = ||x_q||^2 ; qB = x_q^T Binv x_q
__global__ void k_rowq(const float* Xq, const float* Yq, const float* z,
                       const float* cst, float* qn, float* qB) {
  int wave = threadIdx.x / 64, lane = threadIdx.x % 64;
  int q = blockIdx.x * 4 + wave;
  float s1 = 0.0f, s2 = 0.0f;
  const float* xr = Xq + (size_t)q * DD;
  const float* yr = Yq + (size_t)q * DD;
  for (int j = lane; j < DD; j += 64) {
    float xv = xr[j]; s1 += xv * xv;
    float yv = yr[j]; s2 += yv * yv;
  }
  for (int off = 32; off > 0; off >>= 1) {
    s1 += __shfl_down(s1, off);
    s2 += __shfl_down(s2, off);
  }
  if (lane == 0) {
    qn[q] = s1;
    float zq = z[q];
    qB[q] = s2 - cst[10] * zq * zq;
  }
}

__global__ void k_mun(const float* mu, float* mun) {
  int c = blockIdx.x, lane = threadIdx.x;
  float s = 0.0f;
  for (int d = lane; d < DD; d += 64) { float v = mu[(size_t)c * DD + d]; s += v * v; }
  for (int off = 32; off > 0; off >>= 1) s += __shfl_down(s, off);
  if (lane == 0) mun[c] = s;
}

// final epilogue: Woodbury-corrected Mahalanobis -> logits[q,c]
__global__ __launch_bounds__(256) void k_logits(const float* __restrict__ Rg,
    const float* z, const float* zg, const float* Vmu, const float* muBmu,
    const float* mun, const float* qB, const float* qn, const float* xmu,
    const float* Minv, const float* bias, const float* cst, float* out) {
  __shared__ float Ms[289], Vs[17], Zs[17];
  int c = blockIdx.y;
  int q = blockIdx.x * 256 + threadIdx.x;
  for (int t = threadIdx.x; t < 289; t += 256) Ms[t] = Minv[(size_t)c * 289 + t];
  if (threadIdx.x < 17) {
    Vs[threadIdx.x] = Vmu[c * 17 + threadIdx.x];
    Zs[threadIdx.x] = zg[c * 17 + threadIdx.x];
  }
  __syncthreads();
  float csm = cst[10], scale = cst[1], common = cst[2], coef = cst[3];
  float zq = z[q];
  float r[17];
  float xBmu = 0.0f;
  for (int a = 0; a < 17; a++) {
    float raw = Rg[(size_t)(c * 17 + a) * QNQ + q] - csm * Zs[a] * zq;
    if (a == 16) xBmu = raw;
    r[a] = raw - Vs[a];
  }
  float quadB = qB[q] - 2.0f * xBmu + muBmu[c];
  float corr = 0.0f;
  for (int a = 0; a < 17; a++) {
    float e = 0.0f;
    for (int b = 0; b < 17; b++) e += Ms[a * 17 + b] * r[b];
    corr += r[a] * e;
  }
  float distB = (quadB - corr) / scale;
  float dn = qn[q] - 2.0f * xmu[(size_t)q * CNUM + c] + mun[c];
  float dist = (1.0f - REGP) * distB + REGP * dn;
  out[(size_t)q * CNUM + c] = bias[c] - coef * log1pf(dist / common);
}

// ---------------- host ----------------
extern "C" void kernel_launch(void* const* d_in, const int* in_sizes, int n_in,
                              void* d_out, int out_size, void* d_ws, size_t ws_size,
                              hipStream_t stream) {
  const float* Xs    = (const float*)d_in[0];
  const int*   labels= (const int*)d_in[1];
  const float* Xq    = (const float*)d_in[2];
  const float* m     = (const float*)d_in[3];
  const float* kappa = (const float*)d_in[4];
  const float* nu    = (const float*)d_in[5];
  const float* tdiag = (const float*)d_in[6];
  const float* tlow  = (const float*)d_in[7];
  float* ws = (float*)d_ws;
  float* L    = ws + OFF_L;
  float* W    = ws + OFF_W;
  float* mu   = ws + OFF_MU;
  float* Y    = ws + OFF_Y;        // Yq rows 0..2047, Ys 2048..3071, Ymu 3072..3135
  float* z    = ws + OFF_Z;
  float* wm   = ws + OFF_WM;
  float* u    = ws + OFF_U;
  float* cst  = ws + OFF_CONST;
  int*   idx  = (int*)(ws + OFF_IDX);
  float* Yg   = ws + OFF_YG;
  float* zg   = ws + OFF_ZG;
  float* Vmu  = ws + OFF_VMU;
  float* muBmu= ws + OFF_MUBMU;
  float* mun  = ws + OFF_MUN;
  float* G    = ws + OFF_G;
  float* Minv = ws + OFF_MINV;
  float* bias = ws + OFF_BIAS;
  float* qB   = ws + OFF_QB;
  float* qn   = ws + OFF_QNRM;
  float* xmu  = ws + OFF_XMU;
  float* Rg   = ws + OFF_RG;
  float* out  = (float*)d_out;

  k_consts<<<1, 1, 0, stream>>>(kappa, nu, cst);
  k_buildL<<<1024, 256, 0, stream>>>(tdiag, tlow, L);
  k_classidx<<<1, 64, 0, stream>>>(labels, idx);
  k_mu<<<64, 256, 0, stream>>>(Xs, m, idx, cst, mu);
  k_zero<<<1024, 256, 0, stream>>>(W, (size_t)512 * 512);
  k_trinv_diag<<<8, 64, 0, stream>>>(L, W);
  for (int lev = 1; lev < 8; lev++)
    k_trinv_off<<<8 - lev, 256, 0, stream>>>(L, W, lev);
  k_wm<<<512, 64, 0, stream>>>(W, m, wm);
  k_u<<<512, 64, 0, stream>>>(W, wm, u);
  k_smconsts<<<1, 512, 0, stream>>>(L, wm, cst);
  // Y = [Xq; Xs; mu] @ W^T
  gemm_nt<<<dim3(512 / GBN, 2048 / GBM), 256, 0, stream>>>(Xq, W, Y, 2048, 512, 512);
  gemm_nt<<<dim3(512 / GBN, 1024 / GBM), 256, 0, stream>>>(Xs, W, Y + (size_t)2048 * 512, 1024, 512, 512);
  gemm_nt<<<dim3(512 / GBN, 1), 256, 0, stream>>>(mu, W, Y + (size_t)3072 * 512, 64, 512, 512);
  k_z<<<784, 256, 0, stream>>>(Xq, Xs, mu, u, z);
  k_gather<<<1088, 64, 0, stream>>>(Y, z, idx, Yg, zg);
  k_gram<<<64, 256, 0, stream>>>(Yg, zg, cst, G, Vmu, muBmu);
  k_minv<<<64, 64, 0, stream>>>(G, cst, Minv, bias);
  // Rg = Yg (1088x512) @ Yq^T (512x2048)
  gemm_nt<<<dim3(2048 / GBN, (1088 + GBM - 1) / GBM), 256, 0, stream>>>(Yg, Y, Rg, 1088, 2048, 512);
  // xmu = Xq @ mu^T (raw dots for the REG*I term)
  gemm_nt<<<dim3(1, 2048 / GBM), 256, 0, stream>>>(Xq, mu, xmu, 2048, 64, 512);
  k_rowq<<<512, 256, 0, stream>>>(Xq, Y, z, cst, qn, qB);
  k_mun<<<64, 64, 0, stream>>>(mu, mun);
  k_logits<<<dim3(2048 / 256, 64), 256, 0, stream>>>(Rg, z, zg, Vmu, muBmu, mun,
                                                     qB, qn, xmu, Minv, bias, cst, out);
  (void)in_sizes; (void)n_in; (void)out_size; (void)ws_size;
}

// Round 2
// 666.140 us; speedup vs baseline: 1.7390x; 1.7390x over previous
//
#include <hip/hip_runtime.h>
#include <math.h>

// Problem dims (fixed by setup_inputs)
#define DD    512
#define CNUM  64
#define SHOTS 16
#define NSUP  1024
#define QNQ   2048
#define REGP  0.1f

// ---------------- workspace layout (in floats) ----------------
static constexpr size_t OFF_L     = 0;                       // 512*512
static constexpr size_t OFF_W     = OFF_L     + 512*512;     // 512*512
static constexpr size_t OFF_MU    = OFF_W     + 512*512;     // 64*512
static constexpr size_t OFF_Y     = OFF_MU    + 64*512;      // 3136*512 (Yq|Ys|Ymu)
static constexpr size_t OFF_Z     = OFF_Y     + 3136*512;    // 3136
static constexpr size_t OFF_WM    = OFF_Z     + 3136;        // 512
static constexpr size_t OFF_U     = OFF_WM    + 512;         // 512
static constexpr size_t OFF_CONST = OFF_U     + 512;         // 32
static constexpr size_t OFF_IDX   = OFF_CONST + 32;          // 1024 ints
static constexpr size_t OFF_YG    = OFF_IDX   + 1024;        // 1088*512
static constexpr size_t OFF_ZG    = OFF_YG    + 1088*512;    // 1088
static constexpr size_t OFF_VMU   = OFF_ZG    + 1088;        // 1088
static constexpr size_t OFF_MUBMU = OFF_VMU   + 1088;        // 64
static constexpr size_t OFF_MUN   = OFF_MUBMU + 64;          // 64
static constexpr size_t OFF_G     = OFF_MUN   + 64;          // 64*289
static constexpr size_t OFF_MINV  = OFF_G     + 64*289;      // 64*289
static constexpr size_t OFF_BIAS  = OFF_MINV  + 64*289;      // 64
static constexpr size_t OFF_QB    = OFF_BIAS  + 64;          // 2048
static constexpr size_t OFF_QNRM  = OFF_QB    + 2048;        // 2048
static constexpr size_t OFF_XMU   = OFF_QNRM  + 2048;        // 2048*64
static constexpr size_t OFF_RG    = OFF_XMU   + 2048*64;     // 1088*2048

// consts indices: 0 kap, 1 scale, 2 common, 3 coef, 4 bias0, 5 jlast,
// 6 cmu_m, 7 cmu_x, 8 D*log(scale), 9 Jinv_last, 10 c_sm, 11 logdetB

// ---------------- scalar setup ----------------
__global__ void k_consts(const float* kappa, const float* nu, float* cst) {
  float kap = fabsf(kappa[0]) + 1e-6f;
  float nu_ = fmaxf(nu[0], (float)(DD - 1) + 1e-6f);
  float common = nu_ + (float)SHOTS + 1.0f - (float)DD;
  float scale = (kap + SHOTS + 1.0f) / ((nu_ + SHOTS - DD + 1.0f) * (kap + SHOTS));
  cst[0] = kap;
  cst[1] = scale;
  cst[2] = common;
  cst[3] = 0.5f * (common + DD);
  cst[4] = lgammaf(0.5f * (common + DD)) - lgammaf(0.5f * common)
           - 0.5f * (float)DD * logf(common);
  cst[5] = -(kap + SHOTS);             // det(J) = jlast
  cst[6] = kap / (kap + SHOTS);        // mu: m coefficient
  cst[7] = 1.0f / (kap + SHOTS);       // mu: sum(X) coefficient
  cst[8] = (float)DD * logf(scale);
  cst[9] = -1.0f / (kap + SHOTS);      // J^{-1} last diagonal
}

__global__ void k_buildL(const float* tdiag, const float* tlow, float* L) {
  int t = blockIdx.x * 256 + threadIdx.x;
  if (t >= DD * DD) return;
  int i = t / DD, j = t % DD;
  L[t] = (i == j) ? fabsf(tdiag[i]) : (i > j ? tlow[t] : 0.0f);
}

__global__ void k_zero(float* p, size_t n) {
  size_t t = (size_t)blockIdx.x * 256 + threadIdx.x;
  if (t < n) p[t] = 0.0f;
}

// stable per-class index lists via wave ballot (one block per class)
__global__ __launch_bounds__(64) void k_classidx(const int* labels, int* idx) {
  int c = blockIdx.x;
  int lane = threadIdx.x;
  int cnt = 0;
  for (int i0 = 0; i0 < NSUP; i0 += 64) {
    int lab = labels[i0 + lane];
    unsigned long long m = __ballot(lab == c);
    if (lab == c) {
      int pos = cnt + __popcll(m & ((1ull << lane) - 1ull));
      if (pos < SHOTS) idx[c * SHOTS + pos] = i0 + lane;
    }
    cnt += __popcll(m);
  }
}

__global__ void k_mu(const float* Xs, const float* m, const int* idx,
                     const float* cst, float* mu) {
  int c = blockIdx.x;
  float cm = cst[6], cx = cst[7];
  for (int d = threadIdx.x; d < DD; d += 256) {
    float s = 0.0f;
    for (int sh = 0; sh < SHOTS; sh++)
      s += Xs[(size_t)idx[c * SHOTS + sh] * DD + d];
    mu[(size_t)c * DD + d] = cm * m[d] + cx * s;
  }
}

// ---------------- blocked triangular inverse W = L^{-1} ----------------
__global__ __launch_bounds__(64) void k_trinv_diag(const float* L, float* W) {
  __shared__ float Ld[64][65];
  __shared__ float Wd[64][65];
  int jb = blockIdx.x, t = threadIdx.x;
  const float* Lblk = L + (size_t)(jb * 64) * DD + jb * 64;
  for (int r = 0; r < 64; r++) Ld[r][t] = Lblk[(size_t)r * DD + t];
  __syncthreads();
  // thread t owns column t; only reads its own column's earlier rows
  for (int i = 0; i < 64; i++) {
    float w = (i == t) ? 1.0f : 0.0f;
    for (int k = 0; k < i; k++) w -= Ld[i][k] * Wd[k][t];
    Wd[i][t] = w / Ld[i][i];
  }
  __syncthreads();
  float* Wblk = W + (size_t)(jb * 64) * DD + jb * 64;
  for (int r = 0; r < 64; r++) Wblk[(size_t)r * DD + t] = Wd[r][t];
}

// level lev: W[i][j] = -W_ii * (sum_{k=j}^{i-1} L_ik W_kj), i = j + lev
__global__ __launch_bounds__(256) void k_trinv_off(const float* L, float* W, int lev) {
  __shared__ float Ls[64][65];
  __shared__ float Ws[64][65];
  int j = blockIdx.x, i = j + lev;
  int tid = threadIdx.x, tr = tid / 16, tc = tid % 16;
  float acc[4][4] = {};
  for (int kb = j; kb < i; kb++) {
    for (int p = 0; p < 16; p++) {
      int t = tid + 256 * p; int r = t / 64, cc = t % 64;
      Ls[r][cc] = L[(size_t)(i * 64 + r) * DD + kb * 64 + cc];
      Ws[r][cc] = W[(size_t)(kb * 64 + r) * DD + j * 64 + cc];
    }
    __syncthreads();
    for (int k = 0; k < 64; k++) {
      float a[4], b[4];
      for (int x = 0; x < 4; x++) a[x] = Ls[tr * 4 + x][k];
      for (int y = 0; y < 4; y++) b[y] = Ws[k][tc * 4 + y];
      for (int x = 0; x < 4; x++)
        for (int y = 0; y < 4; y++) acc[x][y] += a[x] * b[y];
    }
    __syncthreads();
  }
  // T -> Ls, W_ii -> Ws, then W_ij = -W_ii * T
  for (int x = 0; x < 4; x++)
    for (int y = 0; y < 4; y++) Ls[tr * 4 + x][tc * 4 + y] = acc[x][y];
  for (int p = 0; p < 16; p++) {
    int t = tid + 256 * p; int r = t / 64, cc = t % 64;
    Ws[r][cc] = W[(size_t)(i * 64 + r) * DD + i * 64 + cc];
  }
  __syncthreads();
  float out[4][4] = {};
  for (int k = 0; k < 64; k++) {
    float a[4], b[4];
    for (int x = 0; x < 4; x++) a[x] = Ws[tr * 4 + x][k];
    for (int y = 0; y < 4; y++) b[y] = Ls[k][tc * 4 + y];
    for (int x = 0; x < 4; x++)
      for (int y = 0; y < 4; y++) out[x][y] += a[x] * b[y];
  }
  for (int x = 0; x < 4; x++)
    for (int y = 0; y < 4; y++)
      W[(size_t)(i * 64 + tr * 4 + x) * DD + j * 64 + tc * 4 + y] = -out[x][y];
}

// ---------------- Sherman-Morrison pieces ----------------
__global__ void k_wm(const float* W, const float* m, float* wm) {
  int row = blockIdx.x, lane = threadIdx.x;
  float s = 0.0f;
  for (int j = lane; j < DD; j += 64) s += W[(size_t)row * DD + j] * m[j];
  for (int off = 32; off > 0; off >>= 1) s += __shfl_down(s, off);
  if (lane == 0) wm[row] = s;
}

__global__ void k_u(const float* W, const float* wm, float* u) {
  int j = blockIdx.x, lane = threadIdx.x;
  float s = 0.0f;
  for (int i = lane; i < DD; i += 64) s += W[(size_t)i * DD + j] * wm[i];
  for (int off = 32; off > 0; off >>= 1) s += __shfl_down(s, off);
  if (lane == 0) u[j] = s;
}

__global__ void k_smconsts(const float* L, const float* wm, float* cst) {
  __shared__ float s1[512], s2[512];
  int t = threadIdx.x;
  float a = wm[t] * wm[t];
  float b = logf(fabsf(L[(size_t)t * DD + t]));
  s1[t] = a; s2[t] = b;
  __syncthreads();
  for (int off = 256; off > 0; off >>= 1) {
    if (t < off) { s1[t] += s1[t + off]; s2[t] += s2[t + off]; }
    __syncthreads();
  }
  if (t == 0) {
    float kap = cst[0], ss = s1[0];
    cst[10] = kap / (1.0f + kap * ss);                // Sherman-Morrison coeff
    cst[11] = 2.0f * s2[0] + logf(1.0f + kap * ss);   // logdet(B)
  }
}

// ---------------- fp32 NT GEMM tile body: 128x64, float4 staging ----------------
#define GBM 128
#define GBN 64
#define GBK 16
__device__ __forceinline__ void gemm_tile_body(
    const float* __restrict__ A, int aOff, int aM,
    const float* __restrict__ B, int K, int bn, int kend,
    float* __restrict__ Cc, int cRow0, int N) {
  __shared__ float As[GBK][GBM + 4];   // stride 132: b128-aligned, conflict-free reads
  __shared__ float Bs[GBK][GBN + 4];   // stride 68
  int tid = threadIdx.x, tr = tid >> 4, tc = tid & 15;
  float acc[8][4] = {};
  for (int k0 = 0; k0 < kend; k0 += GBK) {
    #pragma unroll
    for (int p = 0; p < 2; p++) {      // A tile: 128 rows x 16 k = 512 float4
      int u = tid + 256 * p;
      int row = u >> 2, k4 = u & 3;
      int gr = aOff + row;
      float4 v = make_float4(0.f, 0.f, 0.f, 0.f);
      if (gr < aM) v = *(const float4*)(A + (size_t)gr * K + k0 + k4 * 4);
      As[k4 * 4 + 0][row] = v.x; As[k4 * 4 + 1][row] = v.y;
      As[k4 * 4 + 2][row] = v.z; As[k4 * 4 + 3][row] = v.w;
    }
    {                                   // B tile: 64 rows x 16 k = 256 float4
      int row = tid >> 2, k4 = tid & 3;
      float4 v = *(const float4*)(B + (size_t)(bn + row) * K + k0 + k4 * 4);
      Bs[k4 * 4 + 0][row] = v.x; Bs[k4 * 4 + 1][row] = v.y;
      Bs[k4 * 4 + 2][row] = v.z; Bs[k4 * 4 + 3][row] = v.w;
    }
    __syncthreads();
    #pragma unroll
    for (int kk = 0; kk < GBK; kk++) {
      float4 a0 = *(const float4*)&As[kk][tr * 8];
      float4 a1 = *(const float4*)&As[kk][tr * 8 + 4];
      float4 b0 = *(const float4*)&Bs[kk][tc * 4];
      float a[8] = {a0.x, a0.y, a0.z, a0.w, a1.x, a1.y, a1.z, a1.w};
      float b[4] = {b0.x, b0.y, b0.z, b0.w};
      #pragma unroll
      for (int x = 0; x < 8; x++)
        #pragma unroll
        for (int y = 0; y < 4; y++) acc[x][y] += a[x] * b[y];
    }
    __syncthreads();
  }
  #pragma unroll
  for (int x = 0; x < 8; x++) {
    int lr = tr * 8 + x;
    if (aOff + lr < aM) {
      float4 v = make_float4(acc[x][0], acc[x][1], acc[x][2], acc[x][3]);
      *(float4*)(Cc + (size_t)(cRow0 + lr) * N + bn + tc * 4) = v;
    }
  }
}

// generic NT GEMM; tri=1 -> B is lower-triangular (row j zero for k>j)
__global__ __launch_bounds__(256) void gemm_nt(const float* __restrict__ A,
                                               const float* __restrict__ B,
                                               float* __restrict__ Cc,
                                               int M, int N, int K, int tri) {
  int bm = blockIdx.y * GBM, bn = blockIdx.x * GBN;
  int kend = tri ? (bn + GBN) : K;
  gemm_tile_body(A, bm, M, B, K, bn, kend, Cc, bm, N);
}

// fused Y = [Xq; Xs; mu] @ W^T  (W lower-triangular -> kend = bn+64)
__global__ __launch_bounds__(256) void gemm_y(const float* __restrict__ Xq,
                                              const float* __restrict__ Xs,
                                              const float* __restrict__ Mu,
                                              const float* __restrict__ W,
                                              float* __restrict__ Y) {
  int bm = blockIdx.y * GBM, bn = blockIdx.x * GBN;
  const float* A; int aOff, aM;
  if (bm < QNQ)             { A = Xq; aOff = bm;         aM = QNQ;  }
  else if (bm < QNQ + NSUP) { A = Xs; aOff = bm - QNQ;   aM = NSUP; }
  else                      { A = Mu; aOff = bm - QNQ - NSUP; aM = CNUM; }
  gemm_tile_body(A, aOff, aM, W, DD, bn, bn + GBN, Y, bm, DD);
}

// z[r] = F_r . u  over F = [Xq; Xs; mu]
__global__ void k_z(const float* Xq, const float* Xs, const float* mu,
                    const float* u, float* z) {
  int wave = threadIdx.x / 64, lane = threadIdx.x % 64;
  int row = blockIdx.x * 4 + wave;
  if (row >= 3136) return;
  const float* src = (row < QNQ) ? Xq + (size_t)row * DD
                   : (row < QNQ + NSUP) ? Xs + (size_t)(row - QNQ) * DD
                   : mu + (size_t)(row - QNQ - NSUP) * DD;
  float s = 0.0f;
  for (int j = lane; j < DD; j += 64) s += src[j] * u[j];
  for (int off = 32; off > 0; off >>= 1) s += __shfl_down(s, off);
  if (lane == 0) z[row] = s;
}

__global__ void k_gather(const float* Y, const float* z, const int* idx,
                         float* Yg, float* zg) {
  int b = blockIdx.x; int c = b / 17, a = b % 17;
  int src = (a < 16) ? (QNQ + idx[c * SHOTS + a]) : (QNQ + NSUP + c);
  const float* yr = Y + (size_t)src * DD;
  float* yo = Yg + (size_t)b * DD;
  for (int j = threadIdx.x; j < DD; j += 64) yo[j] = yr[j];
  if (threadIdx.x == 0) zg[b] = z[src];
}

// per-class 17x17 Gram (Binv inner products), M = Gram + J^{-1}
__global__ __launch_bounds__(256) void k_gram(const float* Yg, const float* zg,
                                              const float* cst, float* G,
                                              float* Vmu, float* muBmu) {
  __shared__ float Ys[17 * 513];
  __shared__ float zs[17];
  __shared__ float Gs[289];
  int c = blockIdx.x, tid = threadIdx.x;
  for (int t = tid; t < 17 * 512; t += 256) {
    int r = t >> 9, col = t & 511;
    Ys[r * 513 + col] = Yg[((size_t)c * 17 + r) * DD + col];
  }
  if (tid < 17) zs[tid] = zg[c * 17 + tid];
  __syncthreads();
  float csm = cst[10];
  for (int e = tid; e < 289; e += 256) {
    int a = e / 17, b = e % 17;
    const float* ra = &Ys[a * 513];
    const float* rb = &Ys[b * 513];
    float s = 0.0f;
    for (int k = 0; k < 512; k++) s += ra[k] * rb[k];
    Gs[e] = s - csm * zs[a] * zs[b];
  }
  __syncthreads();
  if (tid < 17) Vmu[c * 17 + tid] = Gs[tid * 17 + 16];
  if (tid == 0) muBmu[c] = Gs[16 * 17 + 16];
  __syncthreads();
  if (tid < 17) Gs[tid * 17 + tid] += (tid < 16) ? 1.0f : cst[9];
  __syncthreads();
  for (int t = tid; t < 289; t += 256) G[(size_t)c * 289 + t] = Gs[t];
}

// per-class Gauss-Jordan inverse of M (17x17) + logdet -> bias
__global__ __launch_bounds__(64) void k_minv(const float* G, const float* cst,
                                             float* Minv, float* bias) {
  __shared__ float aug[17][35];
  __shared__ float colk[17];
  __shared__ int pivrow;
  __shared__ float detacc[2];   // [0]=logdet, [1]=sign
  int c = blockIdx.x, lane = threadIdx.x;
  for (int t = lane; t < 289; t += 64) aug[t / 17][t % 17] = G[(size_t)c * 289 + t];
  for (int t = lane; t < 289; t += 64) aug[t / 17][17 + t % 17] = (t / 17 == t % 17) ? 1.0f : 0.0f;
  if (lane == 0) { detacc[0] = 0.0f; detacc[1] = 1.0f; }
  __syncthreads();
  for (int k = 0; k < 17; k++) {
    if (lane == 0) {
      int p = k; float best = fabsf(aug[k][k]);
      for (int r = k + 1; r < 17; r++) {
        float v = fabsf(aug[r][k]);
        if (v > best) { best = v; p = r; }
      }
      pivrow = p;
    }
    __syncthreads();
    int p = pivrow;
    if (p != k) {
      for (int cc = lane; cc < 34; cc += 64) {
        float tmp = aug[k][cc]; aug[k][cc] = aug[p][cc]; aug[p][cc] = tmp;
      }
    }
    __syncthreads();
    if (lane == 0) {
      float piv = aug[k][k];
      detacc[0] += logf(fabsf(piv));
      if (piv < 0.0f) detacc[1] = -detacc[1];
      if (p != k) detacc[1] = -detacc[1];
    }
    if (lane < 17) colk[lane] = aug[lane][k];
    __syncthreads();
    float invp = 1.0f / aug[k][k];
    for (int cc = lane; cc < 34; cc += 64) aug[k][cc] *= invp;
    __syncthreads();
    for (int t = lane; t < 17 * 34; t += 64) {
      int r = t / 34, cc = t % 34;
      if (r != k) aug[r][cc] -= colk[r] * aug[k][cc];
    }
    __syncthreads();
  }
  for (int t = lane; t < 289; t += 64) Minv[(size_t)c * 289 + t] = aug[t / 17][17 + t % 17];
  if (lane == 0) {
    // logdet(sigma_c) = D*log(scale) + logdet(B) + log(det(J)*det(M))
    float slog = logf(fabsf(cst[5])) + detacc[0];  // sign(J det * M det) > 0 (sigma PD)
    float logdetSigma = cst[8] + cst[11] + slog;
    bias[c] = cst[4] - 0.5f * logdetSigma;
  }
}

// per-query norms: qn = ||x_q||^2 ; qB = x_q^T Binv x_q
__global__ void k_rowq(const float* Xq, const float* Yq, const float* z,
                       const float* cst, float* qn, float* qB) {
  int wave = threadIdx.x / 64, lane = threadIdx.x % 64;
  int q = blockIdx.x * 4 + wave;
  float s1 = 0.0f, s2 = 0.0f;
  const float* xr = Xq + (size_t)q * DD;
  const float* yr = Yq + (size_t)q * DD;
  for (int j = lane; j < DD; j += 64) {
    float xv = xr[j]; s1 += xv * xv;
    float yv = yr[j]; s2 += yv * yv;
  }
  for (int off = 32; off > 0; off >>= 1) {
    s1 += __shfl_down(s1, off);
    s2 += __shfl_down(s2, off);
  }
  if (lane == 0) {
    qn[q] = s1;
    float zq = z[q];
    qB[q] = s2 - cst[10] * zq * zq;
  }
}

__global__ void k_mun(const float* mu, float* mun) {
  int c = blockIdx.x, lane = threadIdx.x;
  float s = 0.0f;
  for (int d = lane; d < DD; d += 64) { float v = mu[(size_t)c * DD + d]; s += v * v; }
  for (int off = 32; off > 0; off >>= 1) s += __shfl_down(s, off);
  if (lane == 0) mun[c] = s;
}

// final epilogue: Woodbury-corrected Mahalanobis -> logits[q,c]
__global__ __launch_bounds__(256) void k_logits(const float* __restrict__ Rg,
    const float* z, const float* zg, const float* Vmu, const float* muBmu,
    const float* mun, const float* qB, const float* qn, const float* xmu,
    const float* Minv, const float* bias, const float* cst, float* out) {
  __shared__ float Ms[289], Vs[17], Zs[17];
  int c = blockIdx.y;
  int q = blockIdx.x * 256 + threadIdx.x;
  for (int t = threadIdx.x; t < 289; t += 256) Ms[t] = Minv[(size_t)c * 289 + t];
  if (threadIdx.x < 17) {
    Vs[threadIdx.x] = Vmu[c * 17 + threadIdx.x];
    Zs[threadIdx.x] = zg[c * 17 + threadIdx.x];
  }
  __syncthreads();
  float csm = cst[10], scale = cst[1], common = cst[2], coef = cst[3];
  float zq = z[q];
  float r[17];
  float xBmu = 0.0f;
  for (int a = 0; a < 17; a++) {
    float raw = Rg[(size_t)(c * 17 + a) * QNQ + q] - csm * Zs[a] * zq;
    if (a == 16) xBmu = raw;
    r[a] = raw - Vs[a];
  }
  float quadB = qB[q] - 2.0f * xBmu + muBmu[c];
  float corr = 0.0f;
  for (int a = 0; a < 17; a++) {
    float e = 0.0f;
    for (int b = 0; b < 17; b++) e += Ms[a * 17 + b] * r[b];
    corr += r[a] * e;
  }
  float distB = (quadB - corr) / scale;
  float dn = qn[q] - 2.0f * xmu[(size_t)q * CNUM + c] + mun[c];
  float dist = (1.0f - REGP) * distB + REGP * dn;
  out[(size_t)q * CNUM + c] = bias[c] - coef * log1pf(dist / common);
}

// ---------------- host ----------------
extern "C" void kernel_launch(void* const* d_in, const int* in_sizes, int n_in,
                              void* d_out, int out_size, void* d_ws, size_t ws_size,
                              hipStream_t stream) {
  const float* Xs    = (const float*)d_in[0];
  const int*   labels= (const int*)d_in[1];
  const float* Xq    = (const float*)d_in[2];
  const float* m     = (const float*)d_in[3];
  const float* kappa = (const float*)d_in[4];
  const float* nu    = (const float*)d_in[5];
  const float* tdiag = (const float*)d_in[6];
  const float* tlow  = (const float*)d_in[7];
  float* ws = (float*)d_ws;
  float* L    = ws + OFF_L;
  float* W    = ws + OFF_W;
  float* mu   = ws + OFF_MU;
  float* Y    = ws + OFF_Y;        // Yq rows 0..2047, Ys 2048..3071, Ymu 3072..3135
  float* z    = ws + OFF_Z;
  float* wm   = ws + OFF_WM;
  float* u    = ws + OFF_U;
  float* cst  = ws + OFF_CONST;
  int*   idx  = (int*)(ws + OFF_IDX);
  float* Yg   = ws + OFF_YG;
  float* zg   = ws + OFF_ZG;
  float* Vmu  = ws + OFF_VMU;
  float* muBmu= ws + OFF_MUBMU;
  float* mun  = ws + OFF_MUN;
  float* G    = ws + OFF_G;
  float* Minv = ws + OFF_MINV;
  float* bias = ws + OFF_BIAS;
  float* qB   = ws + OFF_QB;
  float* qn   = ws + OFF_QNRM;
  float* xmu  = ws + OFF_XMU;
  float* Rg   = ws + OFF_RG;
  float* out  = (float*)d_out;

  k_consts<<<1, 1, 0, stream>>>(kappa, nu, cst);
  k_buildL<<<1024, 256, 0, stream>>>(tdiag, tlow, L);
  k_classidx<<<64, 64, 0, stream>>>(labels, idx);
  k_mu<<<64, 256, 0, stream>>>(Xs, m, idx, cst, mu);
  k_zero<<<1024, 256, 0, stream>>>(W, (size_t)512 * 512);
  k_trinv_diag<<<8, 64, 0, stream>>>(L, W);
  for (int lev = 1; lev < 8; lev++)
    k_trinv_off<<<8 - lev, 256, 0, stream>>>(L, W, lev);
  k_wm<<<512, 64, 0, stream>>>(W, m, wm);
  k_u<<<512, 64, 0, stream>>>(W, wm, u);
  k_smconsts<<<1, 512, 0, stream>>>(L, wm, cst);
  // Y = [Xq; Xs; mu] @ W^T  -- one fused launch, triangular K-skip
  gemm_y<<<dim3(DD / GBN, (3136 + GBM - 1) / GBM), 256, 0, stream>>>(Xq, Xs, mu, W, Y);
  k_z<<<784, 256, 0, stream>>>(Xq, Xs, mu, u, z);
  k_gather<<<1088, 64, 0, stream>>>(Y, z, idx, Yg, zg);
  k_gram<<<64, 256, 0, stream>>>(Yg, zg, cst, G, Vmu, muBmu);
  k_minv<<<64, 64, 0, stream>>>(G, cst, Minv, bias);
  // Rg = Yg (1088x512) @ Yq^T (512x2048)
  gemm_nt<<<dim3(QNQ / GBN, (1088 + GBM - 1) / GBM), 256, 0, stream>>>(Yg, Y, Rg, 1088, QNQ, DD, 0);
  // xmu = Xq @ mu^T (raw dots for the REG*I term)
  gemm_nt<<<dim3(CNUM / GBN, QNQ / GBM), 256, 0, stream>>>(Xq, mu, xmu, QNQ, CNUM, DD, 0);
  k_rowq<<<512, 256, 0, stream>>>(Xq, Y, z, cst, qn, qB);
  k_mun<<<64, 64, 0, stream>>>(mu, mun);
  k_logits<<<dim3(QNQ / 256, CNUM), 256, 0, stream>>>(Rg, z, zg, Vmu, muBmu, mun,
                                                      qB, qn, xmu, Minv, bias, cst, out);
  (void)in_sizes; (void)n_in; (void)out_size; (void)ws_size;
}

// Round 3
// 404.040 us; speedup vs baseline: 2.8670x; 1.6487x over previous
//
#include <hip/hip_runtime.h>
#include <math.h>

// Problem dims (fixed by setup_inputs)
#define DD    512
#define CNUM  64
#define SHOTS 16
#define NSUP  1024
#define QNQ   2048
#define REGP  0.1f

// ---------------- workspace layout (in floats) ----------------
static constexpr size_t OFF_L     = 0;                       // 512*512
static constexpr size_t OFF_W     = OFF_L     + 512*512;     // 512*512
static constexpr size_t OFF_MU    = OFF_W     + 512*512;     // 64*512
static constexpr size_t OFF_Y     = OFF_MU    + 64*512;      // 3136*512 (Yq|Ys|Ymu)
static constexpr size_t OFF_Z     = OFF_Y     + 3136*512;    // 3136
static constexpr size_t OFF_WM    = OFF_Z     + 3136;        // 512
static constexpr size_t OFF_U     = OFF_WM    + 512;         // 512
static constexpr size_t OFF_CONST = OFF_U     + 512;         // 32
static constexpr size_t OFF_IDX   = OFF_CONST + 32;          // 1024 ints
static constexpr size_t OFF_YG    = OFF_IDX   + 1024;        // 1088*512
static constexpr size_t OFF_ZG    = OFF_YG    + 1088*512;    // 1088
static constexpr size_t OFF_VMU   = OFF_ZG    + 1088;        // 1088
static constexpr size_t OFF_MUBMU = OFF_VMU   + 1088;        // 64
static constexpr size_t OFF_MUN   = OFF_MUBMU + 64;          // 64
static constexpr size_t OFF_G     = OFF_MUN   + 64;          // 64*289
static constexpr size_t OFF_MINV  = OFF_G     + 64*289;      // 64*289
static constexpr size_t OFF_BIAS  = OFF_MINV  + 64*289;      // 64
static constexpr size_t OFF_QB    = OFF_BIAS  + 64;          // 2048
static constexpr size_t OFF_QNRM  = OFF_QB    + 2048;        // 2048
static constexpr size_t OFF_XMU   = OFF_QNRM  + 2048;        // 2048*64
static constexpr size_t OFF_RG    = OFF_XMU   + 2048*64;     // 1088*2048 (also aliased as trinv T-scratch, disjoint in time)

// consts indices: 0 kap, 1 scale, 2 common, 3 coef, 4 bias0, 5 jlast,
// 6 cmu_m, 7 cmu_x, 8 D*log(scale), 9 Jinv_last, 10 c_sm, 11 logdetB

// ---------------- scalar setup ----------------
__global__ void k_consts(const float* kappa, const float* nu, float* cst) {
  float kap = fabsf(kappa[0]) + 1e-6f;
  float nu_ = fmaxf(nu[0], (float)(DD - 1) + 1e-6f);
  float common = nu_ + (float)SHOTS + 1.0f - (float)DD;
  float scale = (kap + SHOTS + 1.0f) / ((nu_ + SHOTS - DD + 1.0f) * (kap + SHOTS));
  cst[0] = kap;
  cst[1] = scale;
  cst[2] = common;
  cst[3] = 0.5f * (common + DD);
  cst[4] = lgammaf(0.5f * (common + DD)) - lgammaf(0.5f * common)
           - 0.5f * (float)DD * logf(common);
  cst[5] = -(kap + SHOTS);             // det(J) = jlast
  cst[6] = kap / (kap + SHOTS);        // mu: m coefficient
  cst[7] = 1.0f / (kap + SHOTS);       // mu: sum(X) coefficient
  cst[8] = (float)DD * logf(scale);
  cst[9] = -1.0f / (kap + SHOTS);      // J^{-1} last diagonal
}

__global__ void k_buildL(const float* tdiag, const float* tlow, float* L) {
  int t = blockIdx.x * 256 + threadIdx.x;
  if (t >= DD * DD) return;
  int i = t / DD, j = t % DD;
  L[t] = (i == j) ? fabsf(tdiag[i]) : (i > j ? tlow[t] : 0.0f);
}

__global__ void k_zero(float* p, size_t n) {
  size_t t = (size_t)blockIdx.x * 256 + threadIdx.x;
  if (t < n) p[t] = 0.0f;
}

// stable per-class index lists via wave ballot (one block per class)
__global__ __launch_bounds__(64) void k_classidx(const int* labels, int* idx) {
  int c = blockIdx.x;
  int lane = threadIdx.x;
  int cnt = 0;
  for (int i0 = 0; i0 < NSUP; i0 += 64) {
    int lab = labels[i0 + lane];
    unsigned long long m = __ballot(lab == c);
    if (lab == c) {
      int pos = cnt + __popcll(m & ((1ull << lane) - 1ull));
      if (pos < SHOTS) idx[c * SHOTS + pos] = i0 + lane;
    }
    cnt += __popcll(m);
  }
}

__global__ void k_mu(const float* Xs, const float* m, const int* idx,
                     const float* cst, float* mu) {
  int c = blockIdx.x;
  float cm = cst[6], cx = cst[7];
  for (int d = threadIdx.x; d < DD; d += 256) {
    float s = 0.0f;
    for (int sh = 0; sh < SHOTS; sh++)
      s += Xs[(size_t)idx[c * SHOTS + sh] * DD + d];
    mu[(size_t)c * DD + d] = cm * m[d] + cx * s;
  }
}

// ---------------- trinv: diagonal 64-blocks (8 parallel) ----------------
__global__ __launch_bounds__(64) void k_trinv_diag(const float* L, float* W) {
  __shared__ float Ld[64][65];
  __shared__ float Wd[64][65];
  int jb = blockIdx.x, t = threadIdx.x;
  const float* Lblk = L + (size_t)(jb * 64) * DD + jb * 64;
  for (int r = 0; r < 64; r++) Ld[r][t] = Lblk[(size_t)r * DD + t];
  __syncthreads();
  // thread t owns column t; only reads its own column's earlier rows
  for (int i = 0; i < 64; i++) {
    float w = (i == t) ? 1.0f : 0.0f;
    for (int k = 0; k < i; k++) w -= Ld[i][k] * Wd[k][t];
    Wd[i][t] = w / Ld[i][i];
  }
  __syncthreads();
  float* Wblk = W + (size_t)(jb * 64) * DD + jb * 64;
  for (int r = 0; r < 64; r++) Wblk[(size_t)r * DD + t] = Wd[r][t];
}

// ---------------- trinv: recursive doubling GEMM tile (64x64 out) ----------------
// C[64,64] (+)= sgn * A[64, k0:k1] * B[k0:k1, 64]   (NN, runtime strides)
__device__ __forceinline__ void nn64_body(const float* __restrict__ A, int lda,
                                          const float* __restrict__ B, int ldb,
                                          float* __restrict__ Cd, int ldc,
                                          int k0, int k1, float sgn) {
  __shared__ float As[64][68];   // [row][k]  broadcast reads (2-way max = free)
  __shared__ float Bs[64][68];   // [k][col]  b128 reads, stride 68 conflict-free
  int tid = threadIdx.x, tr = tid >> 4, tc = tid & 15;
  float acc[4][4] = {};
  for (int kc = k0; kc < k1; kc += 64) {
    #pragma unroll
    for (int p = 0; p < 4; p++) {
      int f4 = tid + 256 * p;              // 1024 float4 total per tile
      int row = f4 >> 4, c4 = f4 & 15;
      *(float4*)&As[row][c4 * 4] = *(const float4*)(A + (size_t)row * lda + kc + c4 * 4);
      *(float4*)&Bs[row][c4 * 4] = *(const float4*)(B + (size_t)(kc + row) * ldb + c4 * 4);
    }
    __syncthreads();
    #pragma unroll
    for (int kk = 0; kk < 64; kk++) {
      float a[4];
      #pragma unroll
      for (int x = 0; x < 4; x++) a[x] = As[tr * 4 + x][kk];
      float4 bv = *(const float4*)&Bs[kk][tc * 4];
      float b[4] = {bv.x, bv.y, bv.z, bv.w};
      #pragma unroll
      for (int x = 0; x < 4; x++)
        #pragma unroll
        for (int y = 0; y < 4; y++) acc[x][y] += a[x] * b[y];
    }
    __syncthreads();
  }
  #pragma unroll
  for (int x = 0; x < 4; x++) {
    float4 v = make_float4(sgn * acc[x][0], sgn * acc[x][1],
                           sgn * acc[x][2], sgn * acc[x][3]);
    *(float4*)(Cd + (size_t)(tr * 4 + x) * ldc + tc * 4) = v;
  }
}

// level s: T = C * Ainv   (C = L[base+h.., base..], Ainv = W diag super)
// WA lower-triangular -> skip k < tj*64
__global__ __launch_bounds__(256) void k_triT(const float* __restrict__ L,
                                              const float* __restrict__ W,
                                              float* __restrict__ T, int s) {
  int h = s >> 1, tiles = h >> 6, per = tiles * tiles;
  int g = blockIdx.x / per, rem = blockIdx.x % per;
  int ti = rem / tiles, tj = rem % tiles;
  int base = g * s;
  const float* A = L + (size_t)(base + h + ti * 64) * DD + base;
  const float* B = W + (size_t)base * DD + base + tj * 64;
  float* Cd = T + (size_t)g * h * h + (size_t)(ti * 64) * h + tj * 64;
  nn64_body(A, DD, B, DD, Cd, h, tj * 64, h, 1.0f);
}

// level s: X = -Binv * T  (Binv = W diag super at base+h); WB lower-tri -> k <= ti
__global__ __launch_bounds__(256) void k_triX(float* __restrict__ W,
                                              const float* __restrict__ T, int s) {
  int h = s >> 1, tiles = h >> 6, per = tiles * tiles;
  int g = blockIdx.x / per, rem = blockIdx.x % per;
  int ti = rem / tiles, tj = rem % tiles;
  int base = g * s;
  const float* A = W + (size_t)(base + h + ti * 64) * DD + base + h;
  const float* B = T + (size_t)g * h * h + tj * 64;
  float* Cd = W + (size_t)(base + h + ti * 64) * DD + base + tj * 64;
  nn64_body(A, DD, B, h, Cd, DD, 0, (ti + 1) * 64, -1.0f);
}

// ---------------- Sherman-Morrison pieces ----------------
__global__ void k_wm(const float* W, const float* m, float* wm) {
  int row = blockIdx.x, lane = threadIdx.x;
  float s = 0.0f;
  for (int j = lane; j < DD; j += 64) s += W[(size_t)row * DD + j] * m[j];
  for (int off = 32; off > 0; off >>= 1) s += __shfl_down(s, off);
  if (lane == 0) wm[row] = s;
}

__global__ void k_u(const float* W, const float* wm, float* u) {
  int j = blockIdx.x, lane = threadIdx.x;
  float s = 0.0f;
  for (int i = lane; i < DD; i += 64) s += W[(size_t)i * DD + j] * wm[i];
  for (int off = 32; off > 0; off >>= 1) s += __shfl_down(s, off);
  if (lane == 0) u[j] = s;
}

__global__ void k_smconsts(const float* L, const float* wm, float* cst) {
  __shared__ float s1[512], s2[512];
  int t = threadIdx.x;
  float a = wm[t] * wm[t];
  float b = logf(fabsf(L[(size_t)t * DD + t]));
  s1[t] = a; s2[t] = b;
  __syncthreads();
  for (int off = 256; off > 0; off >>= 1) {
    if (t < off) { s1[t] += s1[t + off]; s2[t] += s2[t + off]; }
    __syncthreads();
  }
  if (t == 0) {
    float kap = cst[0], ss = s1[0];
    cst[10] = kap / (1.0f + kap * ss);                // Sherman-Morrison coeff
    cst[11] = 2.0f * s2[0] + logf(1.0f + kap * ss);   // logdet(B)
  }
}

// ---------------- fp32 NT GEMM tile body: 128x64, float4 staging ----------------
#define GBM 128
#define GBN 64
#define GBK 16
__device__ __forceinline__ void gemm_tile_body(
    const float* __restrict__ A, int aOff, int aM,
    const float* __restrict__ B, int K, int bn, int kend,
    float* __restrict__ Cc, int cRow0, int N) {
  __shared__ float As[GBK][GBM + 4];   // stride 132: b128-aligned, conflict-free reads
  __shared__ float Bs[GBK][GBN + 4];   // stride 68
  int tid = threadIdx.x, tr = tid >> 4, tc = tid & 15;
  float acc[8][4] = {};
  for (int k0 = 0; k0 < kend; k0 += GBK) {
    #pragma unroll
    for (int p = 0; p < 2; p++) {      // A tile: 128 rows x 16 k = 512 float4
      int u = tid + 256 * p;
      int row = u >> 2, k4 = u & 3;
      int gr = aOff + row;
      float4 v = make_float4(0.f, 0.f, 0.f, 0.f);
      if (gr < aM) v = *(const float4*)(A + (size_t)gr * K + k0 + k4 * 4);
      As[k4 * 4 + 0][row] = v.x; As[k4 * 4 + 1][row] = v.y;
      As[k4 * 4 + 2][row] = v.z; As[k4 * 4 + 3][row] = v.w;
    }
    {                                   // B tile: 64 rows x 16 k = 256 float4
      int row = tid >> 2, k4 = tid & 3;
      float4 v = *(const float4*)(B + (size_t)(bn + row) * K + k0 + k4 * 4);
      Bs[k4 * 4 + 0][row] = v.x; Bs[k4 * 4 + 1][row] = v.y;
      Bs[k4 * 4 + 2][row] = v.z; Bs[k4 * 4 + 3][row] = v.w;
    }
    __syncthreads();
    #pragma unroll
    for (int kk = 0; kk < GBK; kk++) {
      float4 a0 = *(const float4*)&As[kk][tr * 8];
      float4 a1 = *(const float4*)&As[kk][tr * 8 + 4];
      float4 b0 = *(const float4*)&Bs[kk][tc * 4];
      float a[8] = {a0.x, a0.y, a0.z, a0.w, a1.x, a1.y, a1.z, a1.w};
      float b[4] = {b0.x, b0.y, b0.z, b0.w};
      #pragma unroll
      for (int x = 0; x < 8; x++)
        #pragma unroll
        for (int y = 0; y < 4; y++) acc[x][y] += a[x] * b[y];
    }
    __syncthreads();
  }
  #pragma unroll
  for (int x = 0; x < 8; x++) {
    int lr = tr * 8 + x;
    if (aOff + lr < aM) {
      float4 v = make_float4(acc[x][0], acc[x][1], acc[x][2], acc[x][3]);
      *(float4*)(Cc + (size_t)(cRow0 + lr) * N + bn + tc * 4) = v;
    }
  }
}

// generic NT GEMM
__global__ __launch_bounds__(256) void gemm_nt(const float* __restrict__ A,
                                               const float* __restrict__ B,
                                               float* __restrict__ Cc,
                                               int M, int N, int K, int tri) {
  int bm = blockIdx.y * GBM, bn = blockIdx.x * GBN;
  int kend = tri ? (bn + GBN) : K;
  gemm_tile_body(A, bm, M, B, K, bn, kend, Cc, bm, N);
}

// fused Y = [Xq; Xs; mu] @ W^T  (W lower-triangular -> kend = bn+64)
__global__ __launch_bounds__(256) void gemm_y(const float* __restrict__ Xq,
                                              const float* __restrict__ Xs,
                                              const float* __restrict__ Mu,
                                              const float* __restrict__ W,
                                              float* __restrict__ Y) {
  int bm = blockIdx.y * GBM, bn = blockIdx.x * GBN;
  const float* A; int aOff, aM;
  if (bm < QNQ)             { A = Xq; aOff = bm;         aM = QNQ;  }
  else if (bm < QNQ + NSUP) { A = Xs; aOff = bm - QNQ;   aM = NSUP; }
  else                      { A = Mu; aOff = bm - QNQ - NSUP; aM = CNUM; }
  gemm_tile_body(A, aOff, aM, W, DD, bn, bn + GBN, Y, bm, DD);
}

// z[r] = F_r . u  over F = [Xq; Xs; mu]
__global__ void k_z(const float* Xq, const float* Xs, const float* mu,
                    const float* u, float* z) {
  int wave = threadIdx.x / 64, lane = threadIdx.x % 64;
  int row = blockIdx.x * 4 + wave;
  if (row >= 3136) return;
  const float* src = (row < QNQ) ? Xq + (size_t)row * DD
                   : (row < QNQ + NSUP) ? Xs + (size_t)(row - QNQ) * DD
                   : mu + (size_t)(row - QNQ - NSUP) * DD;
  float s = 0.0f;
  for (int j = lane; j < DD; j += 64) s += src[j] * u[j];
  for (int off = 32; off > 0; off >>= 1) s += __shfl_down(s, off);
  if (lane == 0) z[row] = s;
}

__global__ void k_gather(const float* Y, const float* z, const int* idx,
                         float* Yg, float* zg) {
  int b = blockIdx.x; int c = b / 17, a = b % 17;
  int src = (a < 16) ? (QNQ + idx[c * SHOTS + a]) : (QNQ + NSUP + c);
  const float* yr = Y + (size_t)src * DD;
  float* yo = Yg + (size_t)b * DD;
  for (int j = threadIdx.x; j < DD; j += 64) yo[j] = yr[j];
  if (threadIdx.x == 0) zg[b] = z[src];
}

// per-class 17x17 Gram (Binv inner products), M = Gram + J^{-1}
__global__ __launch_bounds__(256) void k_gram(const float* Yg, const float* zg,
                                              const float* cst, float* G,
                                              float* Vmu, float* muBmu) {
  __shared__ float Ys[17 * 513];
  __shared__ float zs[17];
  __shared__ float Gs[289];
  int c = blockIdx.x, tid = threadIdx.x;
  for (int t = tid; t < 17 * 512; t += 256) {
    int r = t >> 9, col = t & 511;
    Ys[r * 513 + col] = Yg[((size_t)c * 17 + r) * DD + col];
  }
  if (tid < 17) zs[tid] = zg[c * 17 + tid];
  __syncthreads();
  float csm = cst[10];
  for (int e = tid; e < 289; e += 256) {
    int a = e / 17, b = e % 17;
    const float* ra = &Ys[a * 513];
    const float* rb = &Ys[b * 513];
    float s = 0.0f;
    for (int k = 0; k < 512; k++) s += ra[k] * rb[k];
    Gs[e] = s - csm * zs[a] * zs[b];
  }
  __syncthreads();
  if (tid < 17) Vmu[c * 17 + tid] = Gs[tid * 17 + 16];
  if (tid == 0) muBmu[c] = Gs[16 * 17 + 16];
  __syncthreads();
  if (tid < 17) Gs[tid * 17 + tid] += (tid < 16) ? 1.0f : cst[9];
  __syncthreads();
  for (int t = tid; t < 289; t += 256) G[(size_t)c * 289 + t] = Gs[t];
}

// per-class Gauss-Jordan inverse of M (17x17) + logdet -> bias
__global__ __launch_bounds__(64) void k_minv(const float* G, const float* cst,
                                             float* Minv, float* bias) {
  __shared__ float aug[17][35];
  __shared__ float colk[17];
  __shared__ int pivrow;
  __shared__ float detacc[2];   // [0]=logdet, [1]=sign
  int c = blockIdx.x, lane = threadIdx.x;
  for (int t = lane; t < 289; t += 64) aug[t / 17][t % 17] = G[(size_t)c * 289 + t];
  for (int t = lane; t < 289; t += 64) aug[t / 17][17 + t % 17] = (t / 17 == t % 17) ? 1.0f : 0.0f;
  if (lane == 0) { detacc[0] = 0.0f; detacc[1] = 1.0f; }
  __syncthreads();
  for (int k = 0; k < 17; k++) {
    if (lane == 0) {
      int p = k; float best = fabsf(aug[k][k]);
      for (int r = k + 1; r < 17; r++) {
        float v = fabsf(aug[r][k]);
        if (v > best) { best = v; p = r; }
      }
      pivrow = p;
    }
    __syncthreads();
    int p = pivrow;
    if (p != k) {
      for (int cc = lane; cc < 34; cc += 64) {
        float tmp = aug[k][cc]; aug[k][cc] = aug[p][cc]; aug[p][cc] = tmp;
      }
    }
    __syncthreads();
    if (lane == 0) {
      float piv = aug[k][k];
      detacc[0] += logf(fabsf(piv));
      if (piv < 0.0f) detacc[1] = -detacc[1];
      if (p != k) detacc[1] = -detacc[1];
    }
    if (lane < 17) colk[lane] = aug[lane][k];
    __syncthreads();
    float invp = 1.0f / aug[k][k];
    for (int cc = lane; cc < 34; cc += 64) aug[k][cc] *= invp;
    __syncthreads();
    for (int t = lane; t < 17 * 34; t += 64) {
      int r = t / 34, cc = t % 34;
      if (r != k) aug[r][cc] -= colk[r] * aug[k][cc];
    }
    __syncthreads();
  }
  for (int t = lane; t < 289; t += 64) Minv[(size_t)c * 289 + t] = aug[t / 17][17 + t % 17];
  if (lane == 0) {
    // logdet(sigma_c) = D*log(scale) + logdet(B) + log(det(J)*det(M))
    float slog = logf(fabsf(cst[5])) + detacc[0];  // sign(J det * M det) > 0 (sigma PD)
    float logdetSigma = cst[8] + cst[11] + slog;
    bias[c] = cst[4] - 0.5f * logdetSigma;
  }
}

// per-query norms: qn = ||x_q||^2 ; qB = x_q^T Binv x_q
__global__ void k_rowq(const float* Xq, const float* Yq, const float* z,
                       const float* cst, float* qn, float* qB) {
  int wave = threadIdx.x / 64, lane = threadIdx.x % 64;
  int q = blockIdx.x * 4 + wave;
  float s1 = 0.0f, s2 = 0.0f;
  const float* xr = Xq + (size_t)q * DD;
  const float* yr = Yq + (size_t)q * DD;
  for (int j = lane; j < DD; j += 64) {
    float xv = xr[j]; s1 += xv * xv;
    float yv = yr[j]; s2 += yv * yv;
  }
  for (int off = 32; off > 0; off >>= 1) {
    s1 += __shfl_down(s1, off);
    s2 += __shfl_down(s2, off);
  }
  if (lane == 0) {
    qn[q] = s1;
    float zq = z[q];
    qB[q] = s2 - cst[10] * zq * zq;
  }
}

__global__ void k_mun(const float* mu, float* mun) {
  int c = blockIdx.x, lane = threadIdx.x;
  float s = 0.0f;
  for (int d = lane; d < DD; d += 64) { float v = mu[(size_t)c * DD + d]; s += v * v; }
  for (int off = 32; off > 0; off >>= 1) s += __shfl_down(s, off);
  if (lane == 0) mun[c] = s;
}

// final epilogue: Woodbury-corrected Mahalanobis -> logits[q,c]
__global__ __launch_bounds__(256) void k_logits(const float* __restrict__ Rg,
    const float* z, const float* zg, const float* Vmu, const float* muBmu,
    const float* mun, const float* qB, const float* qn, const float* xmu,
    const float* Minv, const float* bias, const float* cst, float* out) {
  __shared__ float Ms[289], Vs[17], Zs[17];
  int c = blockIdx.y;
  int q = blockIdx.x * 256 + threadIdx.x;
  for (int t = threadIdx.x; t < 289; t += 256) Ms[t] = Minv[(size_t)c * 289 + t];
  if (threadIdx.x < 17) {
    Vs[threadIdx.x] = Vmu[c * 17 + threadIdx.x];
    Zs[threadIdx.x] = zg[c * 17 + threadIdx.x];
  }
  __syncthreads();
  float csm = cst[10], scale = cst[1], common = cst[2], coef = cst[3];
  float zq = z[q];
  float r[17];
  float xBmu = 0.0f;
  for (int a = 0; a < 17; a++) {
    float raw = Rg[(size_t)(c * 17 + a) * QNQ + q] - csm * Zs[a] * zq;
    if (a == 16) xBmu = raw;
    r[a] = raw - Vs[a];
  }
  float quadB = qB[q] - 2.0f * xBmu + muBmu[c];
  float corr = 0.0f;
  for (int a = 0; a < 17; a++) {
    float e = 0.0f;
    for (int b = 0; b < 17; b++) e += Ms[a * 17 + b] * r[b];
    corr += r[a] * e;
  }
  float distB = (quadB - corr) / scale;
  float dn = qn[q] - 2.0f * xmu[(size_t)q * CNUM + c] + mun[c];
  float dist = (1.0f - REGP) * distB + REGP * dn;
  out[(size_t)q * CNUM + c] = bias[c] - coef * log1pf(dist / common);
}

// ---------------- host ----------------
extern "C" void kernel_launch(void* const* d_in, const int* in_sizes, int n_in,
                              void* d_out, int out_size, void* d_ws, size_t ws_size,
                              hipStream_t stream) {
  const float* Xs    = (const float*)d_in[0];
  const int*   labels= (const int*)d_in[1];
  const float* Xq    = (const float*)d_in[2];
  const float* m     = (const float*)d_in[3];
  const float* kappa = (const float*)d_in[4];
  const float* nu    = (const float*)d_in[5];
  const float* tdiag = (const float*)d_in[6];
  const float* tlow  = (const float*)d_in[7];
  float* ws = (float*)d_ws;
  float* L    = ws + OFF_L;
  float* W    = ws + OFF_W;
  float* mu   = ws + OFF_MU;
  float* Y    = ws + OFF_Y;        // Yq rows 0..2047, Ys 2048..3071, Ymu 3072..3135
  float* z    = ws + OFF_Z;
  float* wm   = ws + OFF_WM;
  float* u    = ws + OFF_U;
  float* cst  = ws + OFF_CONST;
  int*   idx  = (int*)(ws + OFF_IDX);
  float* Yg   = ws + OFF_YG;
  float* zg   = ws + OFF_ZG;
  float* Vmu  = ws + OFF_VMU;
  float* muBmu= ws + OFF_MUBMU;
  float* mun  = ws + OFF_MUN;
  float* G    = ws + OFF_G;
  float* Minv = ws + OFF_MINV;
  float* bias = ws + OFF_BIAS;
  float* qB   = ws + OFF_QB;
  float* qn   = ws + OFF_QNRM;
  float* xmu  = ws + OFF_XMU;
  float* Rg   = ws + OFF_RG;
  float* Ttmp = ws + OFF_RG;       // trinv scratch, reused (Rg written later)
  float* out  = (float*)d_out;

  k_consts<<<1, 1, 0, stream>>>(kappa, nu, cst);
  k_buildL<<<1024, 256, 0, stream>>>(tdiag, tlow, L);
  k_classidx<<<64, 64, 0, stream>>>(labels, idx);
  k_mu<<<64, 256, 0, stream>>>(Xs, m, idx, cst, mu);
  k_zero<<<1024, 256, 0, stream>>>(W, (size_t)512 * 512);
  // W = L^{-1} via recursive doubling: diag-64 inverses, then 128/256/512 merges
  k_trinv_diag<<<8, 64, 0, stream>>>(L, W);
  for (int s = 128; s <= 512; s <<= 1) {
    int h = s >> 1, tiles = h >> 6, supers = 512 / s;
    int nblk = supers * tiles * tiles;
    k_triT<<<nblk, 256, 0, stream>>>(L, W, Ttmp, s);
    k_triX<<<nblk, 256, 0, stream>>>(W, Ttmp, s);
  }
  k_wm<<<512, 64, 0, stream>>>(W, m, wm);
  k_u<<<512, 64, 0, stream>>>(W, wm, u);
  k_smconsts<<<1, 512, 0, stream>>>(L, wm, cst);
  // Y = [Xq; Xs; mu] @ W^T  -- one fused launch, triangular K-skip
  gemm_y<<<dim3(DD / GBN, (3136 + GBM - 1) / GBM), 256, 0, stream>>>(Xq, Xs, mu, W, Y);
  k_z<<<784, 256, 0, stream>>>(Xq, Xs, mu, u, z);
  k_gather<<<1088, 64, 0, stream>>>(Y, z, idx, Yg, zg);
  k_gram<<<64, 256, 0, stream>>>(Yg, zg, cst, G, Vmu, muBmu);
  k_minv<<<64, 64, 0, stream>>>(G, cst, Minv, bias);
  // Rg = Yg (1088x512) @ Yq^T (512x2048)
  gemm_nt<<<dim3(QNQ / GBN, (1088 + GBM - 1) / GBM), 256, 0, stream>>>(Yg, Y, Rg, 1088, QNQ, DD, 0);
  // xmu = Xq @ mu^T (raw dots for the REG*I term)
  gemm_nt<<<dim3(CNUM / GBN, QNQ / GBM), 256, 0, stream>>>(Xq, mu, xmu, QNQ, CNUM, DD, 0);
  k_rowq<<<512, 256, 0, stream>>>(Xq, Y, z, cst, qn, qB);
  k_mun<<<64, 64, 0, stream>>>(mu, mun);
  k_logits<<<dim3(QNQ / 256, CNUM), 256, 0, stream>>>(Rg, z, zg, Vmu, muBmu, mun,
                                                      qB, qn, xmu, Minv, bias, cst, out);
  (void)in_sizes; (void)n_in; (void)out_size; (void)ws_size;
}

// Round 4
// 362.407 us; speedup vs baseline: 3.1964x; 1.1149x over previous
//
#include <hip/hip_runtime.h>
#include <math.h>

// Problem dims (fixed by setup_inputs)
#define DD    512
#define CNUM  64
#define SHOTS 16
#define NSUP  1024
#define QNQ   2048
#define REGP  0.1f

// ---------------- workspace layout (in floats) ----------------
static constexpr size_t OFF_L     = 0;                       // 512*512
static constexpr size_t OFF_W     = OFF_L     + 512*512;     // 512*512
static constexpr size_t OFF_MU    = OFF_W     + 512*512;     // 64*512
static constexpr size_t OFF_Y     = OFF_MU    + 64*512;      // 3136*512 (Yq|Ys|Ymu)
static constexpr size_t OFF_Z     = OFF_Y     + 3136*512;    // 3136
static constexpr size_t OFF_WM    = OFF_Z     + 3136;        // 512
static constexpr size_t OFF_U     = OFF_WM    + 512;         // 512
static constexpr size_t OFF_CONST = OFF_U     + 512;         // 32
static constexpr size_t OFF_IDX   = OFF_CONST + 32;          // 1024 ints
static constexpr size_t OFF_RMAP  = OFF_IDX   + 1024;        // 1088 ints
static constexpr size_t OFF_VMU   = OFF_RMAP  + 1088;        // 1088
static constexpr size_t OFF_MUBMU = OFF_VMU   + 1088;        // 64
static constexpr size_t OFF_MUN   = OFF_MUBMU + 64;          // 64
static constexpr size_t OFF_G     = OFF_MUN   + 64;          // 64*289
static constexpr size_t OFF_MINV  = OFF_G     + 64*289;      // 64*289
static constexpr size_t OFF_BIAS  = OFF_MINV  + 64*289;      // 64
static constexpr size_t OFF_QB    = OFF_BIAS  + 64;          // 2048
static constexpr size_t OFF_QNRM  = OFF_QB    + 2048;        // 2048
static constexpr size_t OFF_XMU   = OFF_QNRM  + 2048;        // 2048*64
static constexpr size_t OFF_RG    = OFF_XMU   + 2048*64;     // 1088*2048 (K-half 0; also trinv T-scratch earlier)
static constexpr size_t OFF_RG2   = OFF_RG    + 1088*2048;   // 1088*2048 (K-half 1)

// consts indices: 0 kap, 1 scale, 2 common, 3 coef, 4 bias0, 5 jlast,
// 6 cmu_m, 7 cmu_x, 8 D*log(scale), 9 Jinv_last, 10 c_sm, 11 logdetB

// ---------------- scalar setup ----------------
__global__ void k_consts(const float* kappa, const float* nu, float* cst) {
  float kap = fabsf(kappa[0]) + 1e-6f;
  float nu_ = fmaxf(nu[0], (float)(DD - 1) + 1e-6f);
  float common = nu_ + (float)SHOTS + 1.0f - (float)DD;
  float scale = (kap + SHOTS + 1.0f) / ((nu_ + SHOTS - DD + 1.0f) * (kap + SHOTS));
  cst[0] = kap;
  cst[1] = scale;
  cst[2] = common;
  cst[3] = 0.5f * (common + DD);
  cst[4] = lgammaf(0.5f * (common + DD)) - lgammaf(0.5f * common)
           - 0.5f * (float)DD * logf(common);
  cst[5] = -(kap + SHOTS);             // det(J) = jlast
  cst[6] = kap / (kap + SHOTS);        // mu: m coefficient
  cst[7] = 1.0f / (kap + SHOTS);       // mu: sum(X) coefficient
  cst[8] = (float)DD * logf(scale);
  cst[9] = -1.0f / (kap + SHOTS);      // J^{-1} last diagonal
}

// build L and zero W in one pass
__global__ void k_init(const float* tdiag, const float* tlow, float* L, float* W) {
  int t = blockIdx.x * 256 + threadIdx.x;
  if (t >= DD * DD) return;
  int i = t / DD, j = t % DD;
  L[t] = (i == j) ? fabsf(tdiag[i]) : (i > j ? tlow[t] : 0.0f);
  W[t] = 0.0f;
}

// stable per-class index lists via wave ballot (one block per class) + rowmap
__global__ __launch_bounds__(64) void k_classidx(const int* labels, int* idx,
                                                 int* rowmap) {
  int c = blockIdx.x;
  int lane = threadIdx.x;
  int cnt = 0;
  for (int i0 = 0; i0 < NSUP; i0 += 64) {
    int lab = labels[i0 + lane];
    unsigned long long m = __ballot(lab == c);
    if (lab == c) {
      int pos = cnt + __popcll(m & ((1ull << lane) - 1ull));
      if (pos < SHOTS) idx[c * SHOTS + pos] = i0 + lane;
    }
    cnt += __popcll(m);
  }
  __syncthreads();
  if (lane < 17)
    rowmap[c * 17 + lane] = (lane < SHOTS) ? (QNQ + idx[c * SHOTS + lane])
                                           : (QNQ + NSUP + c);
}

// mu + ||mu||^2 fused
__global__ __launch_bounds__(256) void k_mu(const float* Xs, const float* m,
                                            const int* idx, const float* cst,
                                            float* mu, float* mun) {
  __shared__ float red[256];
  int c = blockIdx.x, tid = threadIdx.x;
  float cm = cst[6], cx = cst[7];
  float acc = 0.0f;
  for (int d = tid; d < DD; d += 256) {
    float s = 0.0f;
    for (int sh = 0; sh < SHOTS; sh++)
      s += Xs[(size_t)idx[c * SHOTS + sh] * DD + d];
    float v = cm * m[d] + cx * s;
    mu[(size_t)c * DD + d] = v;
    acc += v * v;
  }
  red[tid] = acc;
  __syncthreads();
  for (int off = 128; off > 0; off >>= 1) {
    if (tid < off) red[tid] += red[tid + off];
    __syncthreads();
  }
  if (tid == 0) mun[c] = red[0];
}

// ---------------- trinv: diagonal 64-blocks (8 parallel) ----------------
__global__ __launch_bounds__(64) void k_trinv_diag(const float* L, float* W) {
  __shared__ float Ld[64][65];
  __shared__ float Wd[64][65];
  int jb = blockIdx.x, t = threadIdx.x;
  const float* Lblk = L + (size_t)(jb * 64) * DD + jb * 64;
  for (int r = 0; r < 64; r++) Ld[r][t] = Lblk[(size_t)r * DD + t];
  __syncthreads();
  for (int i = 0; i < 64; i++) {
    float w = (i == t) ? 1.0f : 0.0f;
    for (int k = 0; k < i; k++) w -= Ld[i][k] * Wd[k][t];
    Wd[i][t] = w / Ld[i][i];
  }
  __syncthreads();
  float* Wblk = W + (size_t)(jb * 64) * DD + jb * 64;
  for (int r = 0; r < 64; r++) Wblk[(size_t)r * DD + t] = Wd[r][t];
}

// ---------------- trinv: recursive doubling GEMM tile (64x64 out) ----------------
__device__ __forceinline__ void nn64_body(const float* __restrict__ A, int lda,
                                          const float* __restrict__ B, int ldb,
                                          float* __restrict__ Cd, int ldc,
                                          int k0, int k1, float sgn) {
  __shared__ float As[64][68];
  __shared__ float Bs[64][68];
  int tid = threadIdx.x, tr = tid >> 4, tc = tid & 15;
  float acc[4][4] = {};
  for (int kc = k0; kc < k1; kc += 64) {
    #pragma unroll
    for (int p = 0; p < 4; p++) {
      int f4 = tid + 256 * p;
      int row = f4 >> 4, c4 = f4 & 15;
      *(float4*)&As[row][c4 * 4] = *(const float4*)(A + (size_t)row * lda + kc + c4 * 4);
      *(float4*)&Bs[row][c4 * 4] = *(const float4*)(B + (size_t)(kc + row) * ldb + c4 * 4);
    }
    __syncthreads();
    #pragma unroll
    for (int kk = 0; kk < 64; kk++) {
      float a[4];
      #pragma unroll
      for (int x = 0; x < 4; x++) a[x] = As[tr * 4 + x][kk];
      float4 bv = *(const float4*)&Bs[kk][tc * 4];
      float b[4] = {bv.x, bv.y, bv.z, bv.w};
      #pragma unroll
      for (int x = 0; x < 4; x++)
        #pragma unroll
        for (int y = 0; y < 4; y++) acc[x][y] += a[x] * b[y];
    }
    __syncthreads();
  }
  #pragma unroll
  for (int x = 0; x < 4; x++) {
    float4 v = make_float4(sgn * acc[x][0], sgn * acc[x][1],
                           sgn * acc[x][2], sgn * acc[x][3]);
    *(float4*)(Cd + (size_t)(tr * 4 + x) * ldc + tc * 4) = v;
  }
}

__global__ __launch_bounds__(256) void k_triT(const float* __restrict__ L,
                                              const float* __restrict__ W,
                                              float* __restrict__ T, int s) {
  int h = s >> 1, tiles = h >> 6, per = tiles * tiles;
  int g = blockIdx.x / per, rem = blockIdx.x % per;
  int ti = rem / tiles, tj = rem % tiles;
  int base = g * s;
  const float* A = L + (size_t)(base + h + ti * 64) * DD + base;
  const float* B = W + (size_t)base * DD + base + tj * 64;
  float* Cd = T + (size_t)g * h * h + (size_t)(ti * 64) * h + tj * 64;
  nn64_body(A, DD, B, DD, Cd, h, tj * 64, h, 1.0f);
}

__global__ __launch_bounds__(256) void k_triX(float* __restrict__ W,
                                              const float* __restrict__ T, int s) {
  int h = s >> 1, tiles = h >> 6, per = tiles * tiles;
  int g = blockIdx.x / per, rem = blockIdx.x % per;
  int ti = rem / tiles, tj = rem % tiles;
  int base = g * s;
  const float* A = W + (size_t)(base + h + ti * 64) * DD + base + h;
  const float* B = T + (size_t)g * h * h + tj * 64;
  float* Cd = W + (size_t)(base + h + ti * 64) * DD + base + tj * 64;
  nn64_body(A, DD, B, h, Cd, DD, 0, (ti + 1) * 64, -1.0f);
}

// ---------------- Sherman-Morrison pieces ----------------
__global__ void k_wm(const float* W, const float* m, float* wm) {
  int row = blockIdx.x, lane = threadIdx.x;
  float s = 0.0f;
  for (int j = lane; j < DD; j += 64) s += W[(size_t)row * DD + j] * m[j];
  for (int off = 32; off > 0; off >>= 1) s += __shfl_down(s, off);
  if (lane == 0) wm[row] = s;
}

// fused: blocks 0..511 compute u[j]; block 512 computes SM consts
__global__ __launch_bounds__(256) void k_uB(const float* W, const float* L,
                                            const float* wm, float* u, float* cst) {
  __shared__ float red[256];
  __shared__ float red2[256];
  int b = blockIdx.x, tid = threadIdx.x;
  if (b < DD) {
    float s = 0.0f;
    for (int i = tid; i < DD; i += 256) s += W[(size_t)i * DD + b] * wm[i];
    red[tid] = s;
    __syncthreads();
    for (int off = 128; off > 0; off >>= 1) {
      if (tid < off) red[tid] += red[tid + off];
      __syncthreads();
    }
    if (tid == 0) u[b] = red[0];
  } else {
    float a = 0.0f, l = 0.0f;
    for (int t = tid; t < DD; t += 256) {
      float w = wm[t]; a += w * w;
      l += logf(fabsf(L[(size_t)t * DD + t]));
    }
    red[tid] = a; red2[tid] = l;
    __syncthreads();
    for (int off = 128; off > 0; off >>= 1) {
      if (tid < off) { red[tid] += red[tid + off]; red2[tid] += red2[tid + off]; }
      __syncthreads();
    }
    if (tid == 0) {
      float kap = cst[0], ss = red[0];
      cst[10] = kap / (1.0f + kap * ss);                // Sherman-Morrison coeff
      cst[11] = 2.0f * red2[0] + logf(1.0f + kap * ss); // logdet(B)
    }
  }
}

// ---------------- fp32 NT GEMM tile body: 128x64, float4 staging ----------------
#define GBM 128
#define GBN 64
#define GBK 16
__device__ __forceinline__ void gemm_tile_body(
    const float* __restrict__ A, int aOff, int aM, const int* __restrict__ amap,
    const float* __restrict__ B, int K, int bn, int k0s, int kend,
    float* __restrict__ Cc, int cRow0, int N) {
  __shared__ float As[GBK][GBM + 4];
  __shared__ float Bs[GBK][GBN + 4];
  int tid = threadIdx.x, tr = tid >> 4, tc = tid & 15;
  // resolve the two A rows this thread stages (gathered if amap)
  int srow[2];
  #pragma unroll
  for (int p = 0; p < 2; p++) {
    int u = tid + 256 * p;
    int row = u >> 2;
    int gr = aOff + row;
    srow[p] = (gr < aM) ? (amap ? amap[gr] : gr) : -1;
  }
  float acc[8][4] = {};
  for (int k0 = k0s; k0 < kend; k0 += GBK) {
    #pragma unroll
    for (int p = 0; p < 2; p++) {
      int u = tid + 256 * p;
      int row = u >> 2, k4 = u & 3;
      float4 v = make_float4(0.f, 0.f, 0.f, 0.f);
      if (srow[p] >= 0) v = *(const float4*)(A + (size_t)srow[p] * K + k0 + k4 * 4);
      As[k4 * 4 + 0][row] = v.x; As[k4 * 4 + 1][row] = v.y;
      As[k4 * 4 + 2][row] = v.z; As[k4 * 4 + 3][row] = v.w;
    }
    {
      int row = tid >> 2, k4 = tid & 3;
      float4 v = *(const float4*)(B + (size_t)(bn + row) * K + k0 + k4 * 4);
      Bs[k4 * 4 + 0][row] = v.x; Bs[k4 * 4 + 1][row] = v.y;
      Bs[k4 * 4 + 2][row] = v.z; Bs[k4 * 4 + 3][row] = v.w;
    }
    __syncthreads();
    #pragma unroll
    for (int kk = 0; kk < GBK; kk++) {
      float4 a0 = *(const float4*)&As[kk][tr * 8];
      float4 a1 = *(const float4*)&As[kk][tr * 8 + 4];
      float4 b0 = *(const float4*)&Bs[kk][tc * 4];
      float a[8] = {a0.x, a0.y, a0.z, a0.w, a1.x, a1.y, a1.z, a1.w};
      float b[4] = {b0.x, b0.y, b0.z, b0.w};
      #pragma unroll
      for (int x = 0; x < 8; x++)
        #pragma unroll
        for (int y = 0; y < 4; y++) acc[x][y] += a[x] * b[y];
    }
    __syncthreads();
  }
  #pragma unroll
  for (int x = 0; x < 8; x++) {
    int lr = tr * 8 + x;
    if (aOff + lr < aM) {
      float4 v = make_float4(acc[x][0], acc[x][1], acc[x][2], acc[x][3]);
      *(float4*)(Cc + (size_t)(cRow0 + lr) * N + bn + tc * 4) = v;
    }
  }
}

// Rg split-K: z-dim selects K half and output buffer; A rows gathered via rowmap
__global__ __launch_bounds__(256) void gemm_rg(const float* __restrict__ Y,
                                               const int* __restrict__ rowmap,
                                               float* __restrict__ Rg,
                                               float* __restrict__ Rg2) {
  int bm = blockIdx.y * GBM, bn = blockIdx.x * GBN;
  int half = blockIdx.z;
  float* out = half ? Rg2 : Rg;
  gemm_tile_body(Y, bm, 17 * CNUM, rowmap, Y, DD, bn, half * 256, half * 256 + 256,
                 out, bm, QNQ);
}

// xmu = Xq @ mu^T
__global__ __launch_bounds__(256) void gemm_xmu(const float* __restrict__ Xq,
                                                const float* __restrict__ Mu,
                                                float* __restrict__ xmu) {
  int bm = blockIdx.y * GBM, bn = blockIdx.x * GBN;
  gemm_tile_body(Xq, bm, QNQ, nullptr, Mu, DD, bn, 0, DD, xmu, bm, CNUM);
}

// fused Y = [Xq; Xs; mu] @ W^T on 64x64 tiles (W lower-tri -> kend = bn+64)
__global__ __launch_bounds__(256) void gemm_y64(const float* __restrict__ Xq,
                                                const float* __restrict__ Xs,
                                                const float* __restrict__ Mu,
                                                const float* __restrict__ W,
                                                float* __restrict__ Y) {
  __shared__ float As[GBK][GBN + 4];
  __shared__ float Bs[GBK][GBN + 4];
  int bm = blockIdx.y * 64, bn = blockIdx.x * 64;
  const float* A; int aOff;
  if (bm < QNQ)             { A = Xq; aOff = bm; }
  else if (bm < QNQ + NSUP) { A = Xs; aOff = bm - QNQ; }
  else                      { A = Mu; aOff = bm - QNQ - NSUP; }
  int tid = threadIdx.x, tr = tid >> 4, tc = tid & 15;
  float acc[4][4] = {};
  int kend = bn + 64;
  for (int k0 = 0; k0 < kend; k0 += GBK) {
    {
      int row = tid >> 2, k4 = tid & 3;
      float4 v = *(const float4*)(A + (size_t)(aOff + row) * DD + k0 + k4 * 4);
      As[k4 * 4 + 0][row] = v.x; As[k4 * 4 + 1][row] = v.y;
      As[k4 * 4 + 2][row] = v.z; As[k4 * 4 + 3][row] = v.w;
      float4 w = *(const float4*)(W + (size_t)(bn + row) * DD + k0 + k4 * 4);
      Bs[k4 * 4 + 0][row] = w.x; Bs[k4 * 4 + 1][row] = w.y;
      Bs[k4 * 4 + 2][row] = w.z; Bs[k4 * 4 + 3][row] = w.w;
    }
    __syncthreads();
    #pragma unroll
    for (int kk = 0; kk < GBK; kk++) {
      float4 a0 = *(const float4*)&As[kk][tr * 4];
      float4 b0 = *(const float4*)&Bs[kk][tc * 4];
      float a[4] = {a0.x, a0.y, a0.z, a0.w};
      float b[4] = {b0.x, b0.y, b0.z, b0.w};
      #pragma unroll
      for (int x = 0; x < 4; x++)
        #pragma unroll
        for (int y = 0; y < 4; y++) acc[x][y] += a[x] * b[y];
    }
    __syncthreads();
  }
  #pragma unroll
  for (int x = 0; x < 4; x++) {
    float4 v = make_float4(acc[x][0], acc[x][1], acc[x][2], acc[x][3]);
    *(float4*)(Y + (size_t)(bm + tr * 4 + x) * DD + bn + tc * 4) = v;
  }
}

// z[r] = F_r . u  over F = [Xq; Xs; mu]
__global__ void k_z(const float* Xq, const float* Xs, const float* mu,
                    const float* u, float* z) {
  int wave = threadIdx.x / 64, lane = threadIdx.x % 64;
  int row = blockIdx.x * 4 + wave;
  if (row >= 3136) return;
  const float* src = (row < QNQ) ? Xq + (size_t)row * DD
                   : (row < QNQ + NSUP) ? Xs + (size_t)(row - QNQ) * DD
                   : mu + (size_t)(row - QNQ - NSUP) * DD;
  float s = 0.0f;
  for (int j = lane; j < DD; j += 64) s += src[j] * u[j];
  for (int off = 32; off > 0; off >>= 1) s += __shfl_down(s, off);
  if (lane == 0) z[row] = s;
}

// per-class 17x17 Gram (gathered from Y), M = Gram + J^{-1}
#define YSTRIDE 516
__global__ __launch_bounds__(256) void k_gram(const float* Y, const float* z,
                                              const int* rowmap, const float* cst,
                                              float* G, float* Vmu, float* muBmu) {
  __shared__ float Ys[17 * YSTRIDE];
  __shared__ float zs[17];
  __shared__ float Gs[289];
  int c = blockIdx.x, tid = threadIdx.x;
  for (int t = tid; t < 17 * 128; t += 256) {
    int r = t >> 7, col = t & 127;
    *(float4*)&Ys[r * YSTRIDE + col * 4] =
        *(const float4*)(Y + (size_t)rowmap[c * 17 + r] * DD + col * 4);
  }
  if (tid < 17) zs[tid] = z[rowmap[c * 17 + tid]];
  __syncthreads();
  float csm = cst[10];
  for (int e = tid; e < 289; e += 256) {
    int a = e / 17, b = e % 17;
    const float* ra = &Ys[a * YSTRIDE];
    const float* rb = &Ys[b * YSTRIDE];
    float s = 0.0f;
    for (int k = 0; k < 128; k++) {
      float4 va = *(const float4*)&ra[k * 4];
      float4 vb = *(const float4*)&rb[k * 4];
      s += va.x * vb.x + va.y * vb.y + va.z * vb.z + va.w * vb.w;
    }
    Gs[e] = s - csm * zs[a] * zs[b];
  }
  __syncthreads();
  if (tid < 17) Vmu[c * 17 + tid] = Gs[tid * 17 + 16];
  if (tid == 0) muBmu[c] = Gs[16 * 17 + 16];
  __syncthreads();
  if (tid < 17) Gs[tid * 17 + tid] += (tid < 16) ? 1.0f : cst[9];
  __syncthreads();
  for (int t = tid; t < 289; t += 256) G[(size_t)c * 289 + t] = Gs[t];
}

// per-class Gauss-Jordan inverse of M (17x17) + logdet -> bias
__global__ __launch_bounds__(64) void k_minv(const float* G, const float* cst,
                                             float* Minv, float* bias) {
  __shared__ float aug[17][35];
  __shared__ float colk[17];
  __shared__ int pivrow;
  __shared__ float detacc[2];
  int c = blockIdx.x, lane = threadIdx.x;
  for (int t = lane; t < 289; t += 64) aug[t / 17][t % 17] = G[(size_t)c * 289 + t];
  for (int t = lane; t < 289; t += 64) aug[t / 17][17 + t % 17] = (t / 17 == t % 17) ? 1.0f : 0.0f;
  if (lane == 0) { detacc[0] = 0.0f; detacc[1] = 1.0f; }
  __syncthreads();
  for (int k = 0; k < 17; k++) {
    if (lane == 0) {
      int p = k; float best = fabsf(aug[k][k]);
      for (int r = k + 1; r < 17; r++) {
        float v = fabsf(aug[r][k]);
        if (v > best) { best = v; p = r; }
      }
      pivrow = p;
    }
    __syncthreads();
    int p = pivrow;
    if (p != k) {
      for (int cc = lane; cc < 34; cc += 64) {
        float tmp = aug[k][cc]; aug[k][cc] = aug[p][cc]; aug[p][cc] = tmp;
      }
    }
    __syncthreads();
    if (lane == 0) {
      float piv = aug[k][k];
      detacc[0] += logf(fabsf(piv));
      if (piv < 0.0f) detacc[1] = -detacc[1];
      if (p != k) detacc[1] = -detacc[1];
    }
    if (lane < 17) colk[lane] = aug[lane][k];
    __syncthreads();
    float invp = 1.0f / aug[k][k];
    for (int cc = lane; cc < 34; cc += 64) aug[k][cc] *= invp;
    __syncthreads();
    for (int t = lane; t < 17 * 34; t += 64) {
      int r = t / 34, cc = t % 34;
      if (r != k) aug[r][cc] -= colk[r] * aug[k][cc];
    }
    __syncthreads();
  }
  for (int t = lane; t < 289; t += 64) Minv[(size_t)c * 289 + t] = aug[t / 17][17 + t % 17];
  if (lane == 0) {
    float slog = logf(fabsf(cst[5])) + detacc[0];
    float logdetSigma = cst[8] + cst[11] + slog;
    bias[c] = cst[4] - 0.5f * logdetSigma;
  }
}

// per-query norms: qn = ||x_q||^2 ; qB = x_q^T Binv x_q
__global__ void k_rowq(const float* Xq, const float* Yq, const float* z,
                       const float* cst, float* qn, float* qB) {
  int wave = threadIdx.x / 64, lane = threadIdx.x % 64;
  int q = blockIdx.x * 4 + wave;
  float s1 = 0.0f, s2 = 0.0f;
  const float* xr = Xq + (size_t)q * DD;
  const float* yr = Yq + (size_t)q * DD;
  for (int j = lane; j < DD; j += 64) {
    float xv = xr[j]; s1 += xv * xv;
    float yv = yr[j]; s2 += yv * yv;
  }
  for (int off = 32; off > 0; off >>= 1) {
    s1 += __shfl_down(s1, off);
    s2 += __shfl_down(s2, off);
  }
  if (lane == 0) {
    qn[q] = s1;
    float zq = z[q];
    qB[q] = s2 - cst[10] * zq * zq;
  }
}

// final epilogue: Woodbury-corrected Mahalanobis -> logits[q,c]
__global__ __launch_bounds__(256) void k_logits(const float* __restrict__ Rg,
    const float* __restrict__ Rg2, const float* z, const int* rowmap,
    const float* Vmu, const float* muBmu, const float* mun, const float* qB,
    const float* qn, const float* xmu, const float* Minv, const float* bias,
    const float* cst, float* out) {
  __shared__ float Ms[289], Vs[17], Zs[17];
  int c = blockIdx.y;
  int q = blockIdx.x * 256 + threadIdx.x;
  for (int t = threadIdx.x; t < 289; t += 256) Ms[t] = Minv[(size_t)c * 289 + t];
  if (threadIdx.x < 17) {
    Vs[threadIdx.x] = Vmu[c * 17 + threadIdx.x];
    Zs[threadIdx.x] = z[rowmap[c * 17 + threadIdx.x]];
  }
  __syncthreads();
  float csm = cst[10], scale = cst[1], common = cst[2], coef = cst[3];
  float zq = z[q];
  float r[17];
  float xBmu = 0.0f;
  for (int a = 0; a < 17; a++) {
    size_t off = (size_t)(c * 17 + a) * QNQ + q;
    float raw = Rg[off] + Rg2[off] - csm * Zs[a] * zq;
    if (a == 16) xBmu = raw;
    r[a] = raw - Vs[a];
  }
  float quadB = qB[q] - 2.0f * xBmu + muBmu[c];
  float corr = 0.0f;
  for (int a = 0; a < 17; a++) {
    float e = 0.0f;
    for (int b = 0; b < 17; b++) e += Ms[a * 17 + b] * r[b];
    corr += r[a] * e;
  }
  float distB = (quadB - corr) / scale;
  float dn = qn[q] - 2.0f * xmu[(size_t)q * CNUM + c] + mun[c];
  float dist = (1.0f - REGP) * distB + REGP * dn;
  out[(size_t)q * CNUM + c] = bias[c] - coef * log1pf(dist / common);
}

// ---------------- host ----------------
extern "C" void kernel_launch(void* const* d_in, const int* in_sizes, int n_in,
                              void* d_out, int out_size, void* d_ws, size_t ws_size,
                              hipStream_t stream) {
  const float* Xs    = (const float*)d_in[0];
  const int*   labels= (const int*)d_in[1];
  const float* Xq    = (const float*)d_in[2];
  const float* m     = (const float*)d_in[3];
  const float* kappa = (const float*)d_in[4];
  const float* nu    = (const float*)d_in[5];
  const float* tdiag = (const float*)d_in[6];
  const float* tlow  = (const float*)d_in[7];
  float* ws = (float*)d_ws;
  float* L    = ws + OFF_L;
  float* W    = ws + OFF_W;
  float* mu   = ws + OFF_MU;
  float* Y    = ws + OFF_Y;
  float* z    = ws + OFF_Z;
  float* wm   = ws + OFF_WM;
  float* u    = ws + OFF_U;
  float* cst  = ws + OFF_CONST;
  int*   idx  = (int*)(ws + OFF_IDX);
  int*   rmap = (int*)(ws + OFF_RMAP);
  float* Vmu  = ws + OFF_VMU;
  float* muBmu= ws + OFF_MUBMU;
  float* mun  = ws + OFF_MUN;
  float* G    = ws + OFF_G;
  float* Minv = ws + OFF_MINV;
  float* bias = ws + OFF_BIAS;
  float* qB   = ws + OFF_QB;
  float* qn   = ws + OFF_QNRM;
  float* xmu  = ws + OFF_XMU;
  float* Rg   = ws + OFF_RG;
  float* Rg2  = ws + OFF_RG2;
  float* Ttmp = ws + OFF_RG;       // trinv scratch, reused (Rg written later)
  float* out  = (float*)d_out;

  k_consts<<<1, 1, 0, stream>>>(kappa, nu, cst);
  k_init<<<1024, 256, 0, stream>>>(tdiag, tlow, L, W);
  k_classidx<<<64, 64, 0, stream>>>(labels, idx, rmap);
  k_mu<<<64, 256, 0, stream>>>(Xs, m, idx, cst, mu, mun);
  // W = L^{-1} via recursive doubling
  k_trinv_diag<<<8, 64, 0, stream>>>(L, W);
  for (int s = 128; s <= 512; s <<= 1) {
    int h = s >> 1, tiles = h >> 6, supers = 512 / s;
    int nblk = supers * tiles * tiles;
    k_triT<<<nblk, 256, 0, stream>>>(L, W, Ttmp, s);
    k_triX<<<nblk, 256, 0, stream>>>(W, Ttmp, s);
  }
  k_wm<<<512, 64, 0, stream>>>(W, m, wm);
  k_uB<<<513, 256, 0, stream>>>(W, L, wm, u, cst);
  // Y = [Xq; Xs; mu] @ W^T  -- 64x64 tiles, triangular K-skip
  gemm_y64<<<dim3(DD / 64, 3136 / 64), 256, 0, stream>>>(Xq, Xs, mu, W, Y);
  k_z<<<784, 256, 0, stream>>>(Xq, Xs, mu, u, z);
  k_gram<<<64, 256, 0, stream>>>(Y, z, rmap, cst, G, Vmu, muBmu);
  k_minv<<<64, 64, 0, stream>>>(G, cst, Minv, bias);
  // Rg = Yg (gathered 1088x512) @ Yq^T, split-K=2 in one dispatch
  gemm_rg<<<dim3(QNQ / GBN, (17 * CNUM + GBM - 1) / GBM, 2), 256, 0, stream>>>(Y, rmap, Rg, Rg2);
  gemm_xmu<<<dim3(CNUM / GBN, QNQ / GBM), 256, 0, stream>>>(Xq, mu, xmu);
  k_rowq<<<512, 256, 0, stream>>>(Xq, Y, z, cst, qn, qB);
  k_logits<<<dim3(QNQ / 256, CNUM), 256, 0, stream>>>(Rg, Rg2, z, rmap, Vmu, muBmu,
                                                      mun, qB, qn, xmu, Minv, bias,
                                                      cst, out);
  (void)in_sizes; (void)n_in; (void)out_size; (void)ws_size;
}

// Round 5
// 318.824 us; speedup vs baseline: 3.6333x; 1.1367x over previous
//
#include <hip/hip_runtime.h>
#include <math.h>

// Problem dims (fixed by setup_inputs)
#define DD    512
#define CNUM  64
#define SHOTS 16
#define NSUP  1024
#define QNQ   2048
#define REGP  0.1f
#define XKS   4      // xmu split-K parts

// ---------------- workspace layout (in floats) ----------------
static constexpr size_t OFF_L     = 0;                       // 512*512
static constexpr size_t OFF_W     = OFF_L     + 512*512;     // 512*512
static constexpr size_t OFF_MU    = OFF_W     + 512*512;     // 64*512
static constexpr size_t OFF_Y     = OFF_MU    + 64*512;      // 3136*512 (Yq|Ys|Ymu)
static constexpr size_t OFF_Z     = OFF_Y     + 3136*512;    // 3136
static constexpr size_t OFF_WM    = OFF_Z     + 3136;        // 512
static constexpr size_t OFF_U     = OFF_WM    + 512;         // 512
static constexpr size_t OFF_CONST = OFF_U     + 512;         // 32
static constexpr size_t OFF_IDX   = OFF_CONST + 32;          // 1024 ints
static constexpr size_t OFF_RMAP  = OFF_IDX   + 1024;        // 1088 ints
static constexpr size_t OFF_VMU   = OFF_RMAP  + 1088;        // 1088
static constexpr size_t OFF_MUBMU = OFF_VMU   + 1088;        // 64
static constexpr size_t OFF_MUN   = OFF_MUBMU + 64;          // 64
static constexpr size_t OFF_G     = OFF_MUN   + 64;          // 64*289
static constexpr size_t OFF_MINV  = OFF_G     + 64*289;      // 64*289
static constexpr size_t OFF_BIAS  = OFF_MINV  + 64*289;      // 64
static constexpr size_t OFF_QB    = OFF_BIAS  + 64;          // 2048
static constexpr size_t OFF_QNRM  = OFF_QB    + 2048;        // 2048
static constexpr size_t OFF_XMU   = OFF_QNRM  + 2048;        // XKS*2048*64 partials
static constexpr size_t OFF_RG    = OFF_XMU   + (size_t)XKS*2048*64; // 1088*2048
static constexpr size_t OFF_RG2   = OFF_RG    + 1088*2048;   // 1088*2048

// consts indices: 0 kap, 1 scale, 2 common, 3 coef, 4 bias0, 5 jlast,
// 6 cmu_m, 7 cmu_x, 8 D*log(scale), 9 Jinv_last, 10 c_sm, 11 logdetB

// ---------------- scalar setup ----------------
__global__ void k_consts(const float* kappa, const float* nu, float* cst) {
  float kap = fabsf(kappa[0]) + 1e-6f;
  float nu_ = fmaxf(nu[0], (float)(DD - 1) + 1e-6f);
  float common = nu_ + (float)SHOTS + 1.0f - (float)DD;
  float scale = (kap + SHOTS + 1.0f) / ((nu_ + SHOTS - DD + 1.0f) * (kap + SHOTS));
  cst[0] = kap;
  cst[1] = scale;
  cst[2] = common;
  cst[3] = 0.5f * (common + DD);
  cst[4] = lgammaf(0.5f * (common + DD)) - lgammaf(0.5f * common)
           - 0.5f * (float)DD * logf(common);
  cst[5] = -(kap + SHOTS);
  cst[6] = kap / (kap + SHOTS);
  cst[7] = 1.0f / (kap + SHOTS);
  cst[8] = (float)DD * logf(scale);
  cst[9] = -1.0f / (kap + SHOTS);
}

// build L and zero W in one pass
__global__ void k_init(const float* tdiag, const float* tlow, float* L, float* W) {
  int t = blockIdx.x * 256 + threadIdx.x;
  if (t >= DD * DD) return;
  int i = t / DD, j = t % DD;
  L[t] = (i == j) ? fabsf(tdiag[i]) : (i > j ? tlow[t] : 0.0f);
  W[t] = 0.0f;
}

// stable per-class index lists via wave ballot (one block per class) + rowmap
__global__ __launch_bounds__(64) void k_classidx(const int* labels, int* idx,
                                                 int* rowmap) {
  int c = blockIdx.x;
  int lane = threadIdx.x;
  int cnt = 0;
  for (int i0 = 0; i0 < NSUP; i0 += 64) {
    int lab = labels[i0 + lane];
    unsigned long long m = __ballot(lab == c);
    if (lab == c) {
      int pos = cnt + __popcll(m & ((1ull << lane) - 1ull));
      if (pos < SHOTS) idx[c * SHOTS + pos] = i0 + lane;
    }
    cnt += __popcll(m);
  }
  __syncthreads();
  if (lane < 17)
    rowmap[c * 17 + lane] = (lane < SHOTS) ? (QNQ + idx[c * SHOTS + lane])
                                           : (QNQ + NSUP + c);
}

// mu + ||mu||^2 fused
__global__ __launch_bounds__(256) void k_mu(const float* Xs, const float* m,
                                            const int* idx, const float* cst,
                                            float* mu, float* mun) {
  __shared__ float red[256];
  int c = blockIdx.x, tid = threadIdx.x;
  float cm = cst[6], cx = cst[7];
  float acc = 0.0f;
  for (int d = tid; d < DD; d += 256) {
    float s = 0.0f;
    for (int sh = 0; sh < SHOTS; sh++)
      s += Xs[(size_t)idx[c * SHOTS + sh] * DD + d];
    float v = cm * m[d] + cx * s;
    mu[(size_t)c * DD + d] = v;
    acc += v * v;
  }
  red[tid] = acc;
  __syncthreads();
  for (int off = 128; off > 0; off >>= 1) {
    if (tid < off) red[tid] += red[tid + off];
    __syncthreads();
  }
  if (tid == 0) mun[c] = red[0];
}

// ---------------- trinv: diagonal 64-blocks (8 parallel) ----------------
__global__ __launch_bounds__(64) void k_trinv_diag(const float* L, float* W) {
  __shared__ float Ld[64][65];
  __shared__ float Wd[64][65];
  int jb = blockIdx.x, t = threadIdx.x;
  const float* Lblk = L + (size_t)(jb * 64) * DD + jb * 64;
  for (int r = 0; r < 64; r++) Ld[r][t] = Lblk[(size_t)r * DD + t];
  __syncthreads();
  for (int i = 0; i < 64; i++) {
    float w = (i == t) ? 1.0f : 0.0f;
    for (int k = 0; k < i; k++) w -= Ld[i][k] * Wd[k][t];
    Wd[i][t] = w / Ld[i][i];
  }
  __syncthreads();
  float* Wblk = W + (size_t)(jb * 64) * DD + jb * 64;
  for (int r = 0; r < 64; r++) Wblk[(size_t)r * DD + t] = Wd[r][t];
}

// ---------------- trinv: recursive doubling GEMM tile (64x64 out) ----------------
__device__ __forceinline__ void nn64_body(const float* __restrict__ A, int lda,
                                          const float* __restrict__ B, int ldb,
                                          float* __restrict__ Cd, int ldc,
                                          int k0, int k1, float sgn) {
  __shared__ float As[64][68];
  __shared__ float Bs[64][68];
  int tid = threadIdx.x, tr = tid >> 4, tc = tid & 15;
  float acc[4][4] = {};
  for (int kc = k0; kc < k1; kc += 64) {
    #pragma unroll
    for (int p = 0; p < 4; p++) {
      int f4 = tid + 256 * p;
      int row = f4 >> 4, c4 = f4 & 15;
      *(float4*)&As[row][c4 * 4] = *(const float4*)(A + (size_t)row * lda + kc + c4 * 4);
      *(float4*)&Bs[row][c4 * 4] = *(const float4*)(B + (size_t)(kc + row) * ldb + c4 * 4);
    }
    __syncthreads();
    #pragma unroll
    for (int kk = 0; kk < 64; kk++) {
      float a[4];
      #pragma unroll
      for (int x = 0; x < 4; x++) a[x] = As[tr * 4 + x][kk];
      float4 bv = *(const float4*)&Bs[kk][tc * 4];
      float b[4] = {bv.x, bv.y, bv.z, bv.w};
      #pragma unroll
      for (int x = 0; x < 4; x++)
        #pragma unroll
        for (int y = 0; y < 4; y++) acc[x][y] += a[x] * b[y];
    }
    __syncthreads();
  }
  #pragma unroll
  for (int x = 0; x < 4; x++) {
    float4 v = make_float4(sgn * acc[x][0], sgn * acc[x][1],
                           sgn * acc[x][2], sgn * acc[x][3]);
    *(float4*)(Cd + (size_t)(tr * 4 + x) * ldc + tc * 4) = v;
  }
}

__global__ __launch_bounds__(256) void k_triT(const float* __restrict__ L,
                                              const float* __restrict__ W,
                                              float* __restrict__ T, int s) {
  int h = s >> 1, tiles = h >> 6, per = tiles * tiles;
  int g = blockIdx.x / per, rem = blockIdx.x % per;
  int ti = rem / tiles, tj = rem % tiles;
  int base = g * s;
  const float* A = L + (size_t)(base + h + ti * 64) * DD + base;
  const float* B = W + (size_t)base * DD + base + tj * 64;
  float* Cd = T + (size_t)g * h * h + (size_t)(ti * 64) * h + tj * 64;
  nn64_body(A, DD, B, DD, Cd, h, tj * 64, h, 1.0f);
}

__global__ __launch_bounds__(256) void k_triX(float* __restrict__ W,
                                              const float* __restrict__ T, int s) {
  int h = s >> 1, tiles = h >> 6, per = tiles * tiles;
  int g = blockIdx.x / per, rem = blockIdx.x % per;
  int ti = rem / tiles, tj = rem % tiles;
  int base = g * s;
  const float* A = W + (size_t)(base + h + ti * 64) * DD + base + h;
  const float* B = T + (size_t)g * h * h + tj * 64;
  float* Cd = W + (size_t)(base + h + ti * 64) * DD + base + tj * 64;
  nn64_body(A, DD, B, h, Cd, DD, 0, (ti + 1) * 64, -1.0f);
}

// ---------------- Sherman-Morrison pieces ----------------
__global__ void k_wm(const float* W, const float* m, float* wm) {
  int row = blockIdx.x, lane = threadIdx.x;
  float s = 0.0f;
  for (int j = lane; j < DD; j += 64) s += W[(size_t)row * DD + j] * m[j];
  for (int off = 32; off > 0; off >>= 1) s += __shfl_down(s, off);
  if (lane == 0) wm[row] = s;
}

// fused: blocks 0..511 compute u[j]; block 512 computes SM consts
__global__ __launch_bounds__(256) void k_uB(const float* W, const float* L,
                                            const float* wm, float* u, float* cst) {
  __shared__ float red[256];
  __shared__ float red2[256];
  int b = blockIdx.x, tid = threadIdx.x;
  if (b < DD) {
    float s = 0.0f;
    for (int i = tid; i < DD; i += 256) s += W[(size_t)i * DD + b] * wm[i];
    red[tid] = s;
    __syncthreads();
    for (int off = 128; off > 0; off >>= 1) {
      if (tid < off) red[tid] += red[tid + off];
      __syncthreads();
    }
    if (tid == 0) u[b] = red[0];
  } else {
    float a = 0.0f, l = 0.0f;
    for (int t = tid; t < DD; t += 256) {
      float w = wm[t]; a += w * w;
      l += logf(fabsf(L[(size_t)t * DD + t]));
    }
    red[tid] = a; red2[tid] = l;
    __syncthreads();
    for (int off = 128; off > 0; off >>= 1) {
      if (tid < off) { red[tid] += red[tid + off]; red2[tid] += red2[tid + off]; }
      __syncthreads();
    }
    if (tid == 0) {
      float kap = cst[0], ss = red[0];
      cst[10] = kap / (1.0f + kap * ss);
      cst[11] = 2.0f * red2[0] + logf(1.0f + kap * ss);
    }
  }
}

// ---------------- fp32 NT GEMM tile body: 128x64, float4 staging ----------------
#define GBM 128
#define GBN 64
#define GBK 16
__device__ __forceinline__ void gemm_tile_body(
    const float* __restrict__ A, int aOff, int aM, const int* __restrict__ amap,
    const float* __restrict__ B, int K, int bn, int k0s, int kend,
    float* __restrict__ Cc, int cRow0, int N) {
  __shared__ float As[GBK][GBM + 4];
  __shared__ float Bs[GBK][GBN + 4];
  int tid = threadIdx.x, tr = tid >> 4, tc = tid & 15;
  int srow[2];
  #pragma unroll
  for (int p = 0; p < 2; p++) {
    int u = tid + 256 * p;
    int row = u >> 2;
    int gr = aOff + row;
    srow[p] = (gr < aM) ? (amap ? amap[gr] : gr) : -1;
  }
  float acc[8][4] = {};
  for (int k0 = k0s; k0 < kend; k0 += GBK) {
    #pragma unroll
    for (int p = 0; p < 2; p++) {
      int u = tid + 256 * p;
      int row = u >> 2, k4 = u & 3;
      float4 v = make_float4(0.f, 0.f, 0.f, 0.f);
      if (srow[p] >= 0) v = *(const float4*)(A + (size_t)srow[p] * K + k0 + k4 * 4);
      As[k4 * 4 + 0][row] = v.x; As[k4 * 4 + 1][row] = v.y;
      As[k4 * 4 + 2][row] = v.z; As[k4 * 4 + 3][row] = v.w;
    }
    {
      int row = tid >> 2, k4 = tid & 3;
      float4 v = *(const float4*)(B + (size_t)(bn + row) * K + k0 + k4 * 4);
      Bs[k4 * 4 + 0][row] = v.x; Bs[k4 * 4 + 1][row] = v.y;
      Bs[k4 * 4 + 2][row] = v.z; Bs[k4 * 4 + 3][row] = v.w;
    }
    __syncthreads();
    #pragma unroll
    for (int kk = 0; kk < GBK; kk++) {
      float4 a0 = *(const float4*)&As[kk][tr * 8];
      float4 a1 = *(const float4*)&As[kk][tr * 8 + 4];
      float4 b0 = *(const float4*)&Bs[kk][tc * 4];
      float a[8] = {a0.x, a0.y, a0.z, a0.w, a1.x, a1.y, a1.z, a1.w};
      float b[4] = {b0.x, b0.y, b0.z, b0.w};
      #pragma unroll
      for (int x = 0; x < 8; x++)
        #pragma unroll
        for (int y = 0; y < 4; y++) acc[x][y] += a[x] * b[y];
    }
    __syncthreads();
  }
  #pragma unroll
  for (int x = 0; x < 8; x++) {
    int lr = tr * 8 + x;
    if (aOff + lr < aM) {
      float4 v = make_float4(acc[x][0], acc[x][1], acc[x][2], acc[x][3]);
      *(float4*)(Cc + (size_t)(cRow0 + lr) * N + bn + tc * 4) = v;
    }
  }
}

// Rg split-K: z-dim selects K half and output buffer; A rows gathered via rowmap
__global__ __launch_bounds__(256) void gemm_rg(const float* __restrict__ Y,
                                               const int* __restrict__ rowmap,
                                               float* __restrict__ Rg,
                                               float* __restrict__ Rg2) {
  int bm = blockIdx.y * GBM, bn = blockIdx.x * GBN;
  int half = blockIdx.z;
  float* out = half ? Rg2 : Rg;
  gemm_tile_body(Y, bm, 17 * CNUM, rowmap, Y, DD, bn, half * 256, half * 256 + 256,
                 out, bm, QNQ);
}

// xmu partials: 32 q-rows x 64 classes per block, K split XKS x 128
// grid (QNQ/32, XKS); xmup[kq][q][c]
__global__ __launch_bounds__(256) void gemm_xmu(const float* __restrict__ Xq,
                                                const float* __restrict__ Mu,
                                                float* __restrict__ xmup) {
  __shared__ float As[GBK][32 + 4];
  __shared__ float Bs[GBK][GBN + 4];
  int bm = blockIdx.x * 32;
  int kq = blockIdx.y;
  int tid = threadIdx.x, tr = tid >> 4, tc = tid & 15; // tr: 16 groups of 2 rows, tc: 16 groups of 4 cols
  float acc[2][4] = {};
  int k0s = kq * (DD / XKS), k0e = k0s + DD / XKS;
  for (int k0 = k0s; k0 < k0e; k0 += GBK) {
    if (tid < 128) {                    // A tile: 32 rows x 16 k = 128 float4
      int row = tid >> 2, k4 = tid & 3;
      float4 v = *(const float4*)(Xq + (size_t)(bm + row) * DD + k0 + k4 * 4);
      As[k4 * 4 + 0][row] = v.x; As[k4 * 4 + 1][row] = v.y;
      As[k4 * 4 + 2][row] = v.z; As[k4 * 4 + 3][row] = v.w;
    }
    {                                   // B tile: 64 rows x 16 k = 256 float4
      int row = tid >> 2, k4 = tid & 3;
      float4 v = *(const float4*)(Mu + (size_t)row * DD + k0 + k4 * 4);
      Bs[k4 * 4 + 0][row] = v.x; Bs[k4 * 4 + 1][row] = v.y;
      Bs[k4 * 4 + 2][row] = v.z; Bs[k4 * 4 + 3][row] = v.w;
    }
    __syncthreads();
    #pragma unroll
    for (int kk = 0; kk < GBK; kk++) {
      float a[2] = {As[kk][tr * 2], As[kk][tr * 2 + 1]};
      float4 b0 = *(const float4*)&Bs[kk][tc * 4];
      float b[4] = {b0.x, b0.y, b0.z, b0.w};
      #pragma unroll
      for (int x = 0; x < 2; x++)
        #pragma unroll
        for (int y = 0; y < 4; y++) acc[x][y] += a[x] * b[y];
    }
    __syncthreads();
  }
  #pragma unroll
  for (int x = 0; x < 2; x++) {
    int q = bm + tr * 2 + x;
    float4 v = make_float4(acc[x][0], acc[x][1], acc[x][2], acc[x][3]);
    *(float4*)(xmup + ((size_t)kq * QNQ + q) * CNUM + tc * 4) = v;
  }
}

// fused Y = [Xq; Xs; mu] @ W^T on 64x64 tiles (W lower-tri -> kend = bn+64)
__global__ __launch_bounds__(256) void gemm_y64(const float* __restrict__ Xq,
                                                const float* __restrict__ Xs,
                                                const float* __restrict__ Mu,
                                                const float* __restrict__ W,
                                                float* __restrict__ Y) {
  __shared__ float As[GBK][GBN + 4];
  __shared__ float Bs[GBK][GBN + 4];
  int bm = blockIdx.y * 64, bn = blockIdx.x * 64;
  const float* A; int aOff;
  if (bm < QNQ)             { A = Xq; aOff = bm; }
  else if (bm < QNQ + NSUP) { A = Xs; aOff = bm - QNQ; }
  else                      { A = Mu; aOff = bm - QNQ - NSUP; }
  int tid = threadIdx.x, tr = tid >> 4, tc = tid & 15;
  float acc[4][4] = {};
  int kend = bn + 64;
  for (int k0 = 0; k0 < kend; k0 += GBK) {
    {
      int row = tid >> 2, k4 = tid & 3;
      float4 v = *(const float4*)(A + (size_t)(aOff + row) * DD + k0 + k4 * 4);
      As[k4 * 4 + 0][row] = v.x; As[k4 * 4 + 1][row] = v.y;
      As[k4 * 4 + 2][row] = v.z; As[k4 * 4 + 3][row] = v.w;
      float4 w = *(const float4*)(W + (size_t)(bn + row) * DD + k0 + k4 * 4);
      Bs[k4 * 4 + 0][row] = w.x; Bs[k4 * 4 + 1][row] = w.y;
      Bs[k4 * 4 + 2][row] = w.z; Bs[k4 * 4 + 3][row] = w.w;
    }
    __syncthreads();
    #pragma unroll
    for (int kk = 0; kk < GBK; kk++) {
      float4 a0 = *(const float4*)&As[kk][tr * 4];
      float4 b0 = *(const float4*)&Bs[kk][tc * 4];
      float a[4] = {a0.x, a0.y, a0.z, a0.w};
      float b[4] = {b0.x, b0.y, b0.z, b0.w};
      #pragma unroll
      for (int x = 0; x < 4; x++)
        #pragma unroll
        for (int y = 0; y < 4; y++) acc[x][y] += a[x] * b[y];
    }
    __syncthreads();
  }
  #pragma unroll
  for (int x = 0; x < 4; x++) {
    float4 v = make_float4(acc[x][0], acc[x][1], acc[x][2], acc[x][3]);
    *(float4*)(Y + (size_t)(bm + tr * 4 + x) * DD + bn + tc * 4) = v;
  }
}

// fused: z[r] = F_r . u over F = [Xq; Xs; mu]; for query rows also qn, qB
__global__ void k_z(const float* Xq, const float* Xs, const float* mu,
                    const float* Y, const float* u, const float* cst,
                    float* z, float* qn, float* qB) {
  int wave = threadIdx.x / 64, lane = threadIdx.x % 64;
  int row = blockIdx.x * 4 + wave;
  if (row >= 3136) return;
  bool isq = row < QNQ;
  const float* src = isq ? Xq + (size_t)row * DD
                   : (row < QNQ + NSUP) ? Xs + (size_t)(row - QNQ) * DD
                   : mu + (size_t)(row - QNQ - NSUP) * DD;
  const float* yr = Y + (size_t)row * DD;
  float s = 0.0f, s1 = 0.0f, s2 = 0.0f;
  for (int j4 = lane; j4 < 128; j4 += 64) {
    float4 v = *(const float4*)(src + j4 * 4);
    float4 uu = *(const float4*)(u + j4 * 4);
    s += v.x * uu.x + v.y * uu.y + v.z * uu.z + v.w * uu.w;
    if (isq) {
      s1 += v.x * v.x + v.y * v.y + v.z * v.z + v.w * v.w;
      float4 yv = *(const float4*)(yr + j4 * 4);
      s2 += yv.x * yv.x + yv.y * yv.y + yv.z * yv.z + yv.w * yv.w;
    }
  }
  for (int off = 32; off > 0; off >>= 1) {
    s += __shfl_down(s, off);
    s1 += __shfl_down(s1, off);
    s2 += __shfl_down(s2, off);
  }
  if (lane == 0) {
    z[row] = s;
    if (isq) {
      qn[row] = s1;
      qB[row] = s2 - cst[10] * s * s;
    }
  }
}

// per-class 17x17 Gram (gathered from Y), M = Gram + J^{-1}
#define YSTRIDE 516
__global__ __launch_bounds__(256) void k_gram(const float* Y, const float* z,
                                              const int* rowmap, const float* cst,
                                              float* G, float* Vmu, float* muBmu) {
  __shared__ float Ys[17 * YSTRIDE];
  __shared__ float zs[17];
  __shared__ float Gs[289];
  int c = blockIdx.x, tid = threadIdx.x;
  for (int t = tid; t < 17 * 128; t += 256) {
    int r = t >> 7, col = t & 127;
    *(float4*)&Ys[r * YSTRIDE + col * 4] =
        *(const float4*)(Y + (size_t)rowmap[c * 17 + r] * DD + col * 4);
  }
  if (tid < 17) zs[tid] = z[rowmap[c * 17 + tid]];
  __syncthreads();
  float csm = cst[10];
  for (int e = tid; e < 289; e += 256) {
    int a = e / 17, b = e % 17;
    const float* ra = &Ys[a * YSTRIDE];
    const float* rb = &Ys[b * YSTRIDE];
    float s = 0.0f;
    for (int k = 0; k < 128; k++) {
      float4 va = *(const float4*)&ra[k * 4];
      float4 vb = *(const float4*)&rb[k * 4];
      s += va.x * vb.x + va.y * vb.y + va.z * vb.z + va.w * vb.w;
    }
    Gs[e] = s - csm * zs[a] * zs[b];
  }
  __syncthreads();
  if (tid < 17) Vmu[c * 17 + tid] = Gs[tid * 17 + 16];
  if (tid == 0) muBmu[c] = Gs[16 * 17 + 16];
  __syncthreads();
  if (tid < 17) Gs[tid * 17 + tid] += (tid < 16) ? 1.0f : cst[9];
  __syncthreads();
  for (int t = tid; t < 289; t += 256) G[(size_t)c * 289 + t] = Gs[t];
}

// per-class Gauss-Jordan inverse of M (17x17) + logdet -> bias
__global__ __launch_bounds__(64) void k_minv(const float* G, const float* cst,
                                             float* Minv, float* bias) {
  __shared__ float aug[17][35];
  __shared__ float colk[17];
  __shared__ int pivrow;
  __shared__ float detacc[2];
  int c = blockIdx.x, lane = threadIdx.x;
  for (int t = lane; t < 289; t += 64) aug[t / 17][t % 17] = G[(size_t)c * 289 + t];
  for (int t = lane; t < 289; t += 64) aug[t / 17][17 + t % 17] = (t / 17 == t % 17) ? 1.0f : 0.0f;
  if (lane == 0) { detacc[0] = 0.0f; detacc[1] = 1.0f; }
  __syncthreads();
  for (int k = 0; k < 17; k++) {
    if (lane == 0) {
      int p = k; float best = fabsf(aug[k][k]);
      for (int r = k + 1; r < 17; r++) {
        float v = fabsf(aug[r][k]);
        if (v > best) { best = v; p = r; }
      }
      pivrow = p;
    }
    __syncthreads();
    int p = pivrow;
    if (p != k) {
      for (int cc = lane; cc < 34; cc += 64) {
        float tmp = aug[k][cc]; aug[k][cc] = aug[p][cc]; aug[p][cc] = tmp;
      }
    }
    __syncthreads();
    if (lane == 0) {
      float piv = aug[k][k];
      detacc[0] += logf(fabsf(piv));
      if (piv < 0.0f) detacc[1] = -detacc[1];
      if (p != k) detacc[1] = -detacc[1];
    }
    if (lane < 17) colk[lane] = aug[lane][k];
    __syncthreads();
    float invp = 1.0f / aug[k][k];
    for (int cc = lane; cc < 34; cc += 64) aug[k][cc] *= invp;
    __syncthreads();
    for (int t = lane; t < 17 * 34; t += 64) {
      int r = t / 34, cc = t % 34;
      if (r != k) aug[r][cc] -= colk[r] * aug[k][cc];
    }
    __syncthreads();
  }
  for (int t = lane; t < 289; t += 64) Minv[(size_t)c * 289 + t] = aug[t / 17][17 + t % 17];
  if (lane == 0) {
    float slog = logf(fabsf(cst[5])) + detacc[0];
    float logdetSigma = cst[8] + cst[11] + slog;
    bias[c] = cst[4] - 0.5f * logdetSigma;
  }
}

// final epilogue: Woodbury-corrected Mahalanobis -> logits[q,c]
__global__ __launch_bounds__(256) void k_logits(const float* __restrict__ Rg,
    const float* __restrict__ Rg2, const float* z, const int* rowmap,
    const float* Vmu, const float* muBmu, const float* mun, const float* qB,
    const float* qn, const float* xmup, const float* Minv, const float* bias,
    const float* cst, float* out) {
  __shared__ float Ms[289], Vs[17], Zs[17];
  int c = blockIdx.y;
  int q = blockIdx.x * 256 + threadIdx.x;
  for (int t = threadIdx.x; t < 289; t += 256) Ms[t] = Minv[(size_t)c * 289 + t];
  if (threadIdx.x < 17) {
    Vs[threadIdx.x] = Vmu[c * 17 + threadIdx.x];
    Zs[threadIdx.x] = z[rowmap[c * 17 + threadIdx.x]];
  }
  __syncthreads();
  float csm = cst[10], scale = cst[1], common = cst[2], coef = cst[3];
  float zq = z[q];
  float r[17];
  float xBmu = 0.0f;
  for (int a = 0; a < 17; a++) {
    size_t off = (size_t)(c * 17 + a) * QNQ + q;
    float raw = Rg[off] + Rg2[off] - csm * Zs[a] * zq;
    if (a == 16) xBmu = raw;
    r[a] = raw - Vs[a];
  }
  float quadB = qB[q] - 2.0f * xBmu + muBmu[c];
  float corr = 0.0f;
  for (int a = 0; a < 17; a++) {
    float e = 0.0f;
    for (int b = 0; b < 17; b++) e += Ms[a * 17 + b] * r[b];
    corr += r[a] * e;
  }
  float distB = (quadB - corr) / scale;
  float xm = 0.0f;
  #pragma unroll
  for (int p = 0; p < XKS; p++)
    xm += xmup[((size_t)p * QNQ + q) * CNUM + c];
  float dn = qn[q] - 2.0f * xm + mun[c];
  float dist = (1.0f - REGP) * distB + REGP * dn;
  out[(size_t)q * CNUM + c] = bias[c] - coef * log1pf(dist / common);
}

// ---------------- host ----------------
extern "C" void kernel_launch(void* const* d_in, const int* in_sizes, int n_in,
                              void* d_out, int out_size, void* d_ws, size_t ws_size,
                              hipStream_t stream) {
  const float* Xs    = (const float*)d_in[0];
  const int*   labels= (const int*)d_in[1];
  const float* Xq    = (const float*)d_in[2];
  const float* m     = (const float*)d_in[3];
  const float* kappa = (const float*)d_in[4];
  const float* nu    = (const float*)d_in[5];
  const float* tdiag = (const float*)d_in[6];
  const float* tlow  = (const float*)d_in[7];
  float* ws = (float*)d_ws;
  float* L    = ws + OFF_L;
  float* W    = ws + OFF_W;
  float* mu   = ws + OFF_MU;
  float* Y    = ws + OFF_Y;
  float* z    = ws + OFF_Z;
  float* wm   = ws + OFF_WM;
  float* u    = ws + OFF_U;
  float* cst  = ws + OFF_CONST;
  int*   idx  = (int*)(ws + OFF_IDX);
  int*   rmap = (int*)(ws + OFF_RMAP);
  float* Vmu  = ws + OFF_VMU;
  float* muBmu= ws + OFF_MUBMU;
  float* mun  = ws + OFF_MUN;
  float* G    = ws + OFF_G;
  float* Minv = ws + OFF_MINV;
  float* bias = ws + OFF_BIAS;
  float* qB   = ws + OFF_QB;
  float* qn   = ws + OFF_QNRM;
  float* xmup = ws + OFF_XMU;
  float* Rg   = ws + OFF_RG;
  float* Rg2  = ws + OFF_RG2;
  float* Ttmp = ws + OFF_RG;       // trinv scratch, reused (Rg written later)
  float* out  = (float*)d_out;

  k_consts<<<1, 1, 0, stream>>>(kappa, nu, cst);
  k_init<<<1024, 256, 0, stream>>>(tdiag, tlow, L, W);
  k_classidx<<<64, 64, 0, stream>>>(labels, idx, rmap);
  k_mu<<<64, 256, 0, stream>>>(Xs, m, idx, cst, mu, mun);
  // W = L^{-1} via recursive doubling
  k_trinv_diag<<<8, 64, 0, stream>>>(L, W);
  for (int s = 128; s <= 512; s <<= 1) {
    int h = s >> 1, tiles = h >> 6, supers = 512 / s;
    int nblk = supers * tiles * tiles;
    k_triT<<<nblk, 256, 0, stream>>>(L, W, Ttmp, s);
    k_triX<<<nblk, 256, 0, stream>>>(W, Ttmp, s);
  }
  k_wm<<<512, 64, 0, stream>>>(W, m, wm);
  k_uB<<<513, 256, 0, stream>>>(W, L, wm, u, cst);
  // Y = [Xq; Xs; mu] @ W^T  -- 64x64 tiles, triangular K-skip
  gemm_y64<<<dim3(DD / 64, 3136 / 64), 256, 0, stream>>>(Xq, Xs, mu, W, Y);
  k_z<<<784, 256, 0, stream>>>(Xq, Xs, mu, Y, u, cst, z, qn, qB);
  k_gram<<<64, 256, 0, stream>>>(Y, z, rmap, cst, G, Vmu, muBmu);
  k_minv<<<64, 64, 0, stream>>>(G, cst, Minv, bias);
  // Rg = Yg (gathered 1088x512) @ Yq^T, split-K=2 in one dispatch
  gemm_rg<<<dim3(QNQ / GBN, (17 * CNUM + GBM - 1) / GBM, 2), 256, 0, stream>>>(Y, rmap, Rg, Rg2);
  // xmu = Xq @ mu^T, 32-row tiles, split-K=4 -> 256 blocks
  gemm_xmu<<<dim3(QNQ / 32, XKS), 256, 0, stream>>>(Xq, mu, xmup);
  k_logits<<<dim3(QNQ / 256, CNUM), 256, 0, stream>>>(Rg, Rg2, z, rmap, Vmu, muBmu,
                                                      mun, qB, qn, xmup, Minv, bias,
                                                      cst, out);
  (void)in_sizes; (void)n_in; (void)out_size; (void)ws_size;
}